// Round 7
// baseline (827.256 us; speedup 1.0000x reference)
//
#include <hip/hip_runtime.h>
#include <hip/hip_bf16.h>
#include <cstdint>

#define DH 128   // hidden dim
#define NB 256   // partition blocks for CSR build
#define NBK 1024 // max buckets (N <= 131072)

typedef __attribute__((ext_vector_type(8))) short short8;
typedef __attribute__((ext_vector_type(4))) float floatx4;
typedef __attribute__((ext_vector_type(2))) float floatx2;

__device__ __forceinline__ float bflo(unsigned u) { return __uint_as_float(u << 16); }
__device__ __forceinline__ float bfhi(unsigned u) { return __uint_as_float(u & 0xffff0000u); }

__device__ __forceinline__ unsigned pk_bf16(float a, float b) {
  return ((unsigned)__bfloat16_as_ushort(__float2bfloat16(b)) << 16)
       | (unsigned)__bfloat16_as_ushort(__float2bfloat16(a));
}

// ---------------- zero-fill ----------------

__global__ void zero_i32(int* __restrict__ p, int n) {
  int i = blockIdx.x * 256 + threadIdx.x;
  if (i < n) p[i] = 0;
}

// ---------------- fp32 -> bf16 convert ----------------

__global__ void cvt_bf16(const float* __restrict__ x, __hip_bfloat16* __restrict__ o, int n) {
  int i = blockIdx.x * 256 + threadIdx.x;
  if (i < n) o[i] = __float2bfloat16(x[i]);
}

// ---------------- scans (generic, reused) ----------------

__global__ void hist_kernel(const int* __restrict__ dst, int* __restrict__ deg, int E) {
  int e = blockIdx.x * 256 + threadIdx.x;
  if (e < E) atomicAdd(&deg[dst[e]], 1);
}

__global__ void scan1_kernel(const int* __restrict__ deg, int* __restrict__ off,
                             int* __restrict__ bsum, int n) {
  __shared__ int sh[256];
  int idx = blockIdx.x * 256 + threadIdx.x;
  int v = (idx < n) ? deg[idx] : 0;
  sh[threadIdx.x] = v;
  __syncthreads();
  for (int d = 1; d < 256; d <<= 1) {
    int x = (threadIdx.x >= (unsigned)d) ? sh[threadIdx.x - d] : 0;
    __syncthreads();
    sh[threadIdx.x] += x;
    __syncthreads();
  }
  if (idx < n) off[idx] = sh[threadIdx.x] - v;   // exclusive
  if (threadIdx.x == 255) bsum[blockIdx.x] = sh[255];
}

__global__ void scan2_kernel(int* __restrict__ bsum, int nb) {
  __shared__ int sh[512];
  int t = threadIdx.x;
  int v = (t < nb) ? bsum[t] : 0;
  sh[t] = v;
  __syncthreads();
  for (int d = 1; d < 512; d <<= 1) {
    int x = (t >= (unsigned)d) ? sh[t - d] : 0;
    __syncthreads();
    sh[t] += x;
    __syncthreads();
  }
  if (t < nb) bsum[t] = sh[t] - v;
}

__global__ void scan3_kernel(int* __restrict__ off, const int* __restrict__ bsum, int n) {
  int idx = blockIdx.x * 256 + threadIdx.x;
  if (idx < n) off[idx] += bsum[blockIdx.x];
}

// ---------------- atomic-free CSR build (counting sort by dst>>7) ----------------

__global__ __launch_bounds__(256)
void csr_p1(const int* __restrict__ dst, int* __restrict__ hist, int E, int chunk) {
  __shared__ int cnt[NBK];
  const int blk = blockIdx.x, tid = threadIdx.x;
  for (int c = tid; c < NBK; c += 256) cnt[c] = 0;
  __syncthreads();
  int base = blk * chunk;
  int end = base + chunk; if (end > E) end = E;
  for (int e = base + tid; e < end; e += 256) atomicAdd(&cnt[dst[e] >> 7], 1);
  __syncthreads();
  for (int c = tid; c < NBK; c += 256) hist[blk * NBK + c] = cnt[c];
}

__global__ __launch_bounds__(256)
void csr_p2(int* __restrict__ hist, int* __restrict__ total) {
  int b = blockIdx.x * 256 + threadIdx.x;   // bucket id
  int run = 0;
  for (int blk = 0; blk < NB; ++blk) {
    int v = hist[blk * NBK + b];
    hist[blk * NBK + b] = run;
    run += v;
  }
  total[b] = run;
}

__global__ __launch_bounds__(256)
void csr_p3(const int* __restrict__ src, const int* __restrict__ dst,
            const int* __restrict__ hist, const int* __restrict__ tstart,
            int* __restrict__ part, int E, int chunk) {
  __shared__ int cur[NBK];
  const int blk = blockIdx.x, tid = threadIdx.x;
  for (int c = tid; c < NBK; c += 256) cur[c] = hist[blk * NBK + c] + tstart[c];
  __syncthreads();
  int base = blk * chunk;
  int end = base + chunk; if (end > E) end = E;
  for (int e = base + tid; e < end; e += 256) {
    int d = dst[e];
    int b = d >> 7;
    int pos = atomicAdd(&cur[b], 1);     // LDS atomic
    part[pos] = (src[e] << 7) | (d & 127);
  }
}

__global__ __launch_bounds__(256)
void csr_p4(const int* __restrict__ part, const int* __restrict__ tstart,
            const int* __restrict__ total, int* __restrict__ deg,
            int* __restrict__ off, int* __restrict__ csr, int Nn) {
  __shared__ int lcnt[128], lscan[128], lcur[128];
  const int b = blockIdx.x, tid = threadIdx.x;
  const int p0 = tstart[b];
  const int m = total[b];
  if (tid < 128) lcnt[tid] = 0;
  __syncthreads();
  for (int k = tid; k < m; k += 256) atomicAdd(&lcnt[part[p0 + k] & 127], 1);
  __syncthreads();
  if (tid < 128) lscan[tid] = lcnt[tid];
  __syncthreads();
  for (int d = 1; d < 128; d <<= 1) {
    int v = 0;
    if (tid < 128 && tid >= d) v = lscan[tid - d];
    __syncthreads();
    if (tid < 128) lscan[tid] += v;
    __syncthreads();
  }
  if (tid < 128) {
    int ex = lscan[tid] - lcnt[tid];
    lcur[tid] = ex;
    int n = (b << 7) + tid;
    if (n < Nn) { deg[n] = lcnt[tid]; off[n] = p0 + ex; }
  }
  __syncthreads();
  for (int k = tid; k < m; k += 256) {
    int pk = part[p0 + k];
    int pos = p0 + atomicAdd(&lcur[pk & 127], 1);   // LDS atomic
    csr[pos] = pk >> 7;
  }
}

// ---------------- weight packing: WT[512][128] bf16 = [Wq|Wk|Wv|Ws]^T ----------------

__global__ void pack_w_kernel(const float* __restrict__ Wq, const float* __restrict__ Wk,
                              const float* __restrict__ Wv, const float* __restrict__ Ws,
                              const float* __restrict__ bq, const float* __restrict__ bk,
                              const float* __restrict__ bv, const float* __restrict__ bs,
                              __hip_bfloat16* __restrict__ WT, float* __restrict__ bcat) {
  int idx = blockIdx.x * 256 + threadIdx.x;
  if (idx < 512 * DH) {
    int c = idx >> 7, k = idx & 127;
    int which = c >> 7, cc = c & 127;
    const float* W = (which == 0) ? Wq : (which == 1) ? Wk : (which == 2) ? Wv : Ws;
    WT[idx] = __float2bfloat16(W[k * DH + cc]);
    if (k == 0) {
      const float* b = (which == 0) ? bq : (which == 1) ? bk : (which == 2) ? bv : bs;
      bcat[c] = b[cc];
    }
  }
}

// ---------------- fused QKVS GEMM (TRANSPOSED MFMA: D[wcol][node]) ----------------
// kvp layout per node: 16 uint4 (lane t16): {k[8t..+3], v[8t..+3], k[8t+4..+7], v[8t+4..+7]} fp8

__global__ __launch_bounds__(256)
void gemm_qkvs(const short* __restrict__ Xb, const short* __restrict__ WT,
               const float* __restrict__ bc,
               unsigned int* __restrict__ qout,
               unsigned int* __restrict__ kvp,
               unsigned int* __restrict__ xrout, int Nn) {
  const int row0 = blockIdx.x * 64;
  const int tid = threadIdx.x;
  const int w = tid >> 6, lane = tid & 63, quad = lane >> 4, l16 = lane & 15;

  // B-operand: X fragments, 4 node-tiles x 4 k-chunks (16B contiguous per lane)
  short8 xf[4][4];
#pragma unroll
  for (int nt = 0; nt < 4; ++nt) {
    int node = row0 + nt * 16 + l16; if (node >= Nn) node = Nn - 1;
#pragma unroll
    for (int kt = 0; kt < 4; ++kt)
      xf[nt][kt] = *(const short8*)&Xb[(size_t)node * 128 + kt * 32 + quad * 8];
  }

  if (w == 0 || w == 3) {
    unsigned int* outp = (w == 0) ? qout : xrout;
    const int mbase = (w == 0) ? 0 : 24;
#pragma unroll
    for (int i = 0; i < 8; ++i) {
      const int mt = mbase + i;
      short8 af[4];
#pragma unroll
      for (int kt = 0; kt < 4; ++kt)
        af[kt] = *(const short8*)&WT[(size_t)(mt * 16 + l16) * 128 + kt * 32 + quad * 8];
      float4 bias = *(const float4*)&bc[mt * 16 + quad * 4];
      const int wc = (i * 16 + quad * 4);   // col within 128-col segment
#pragma unroll
      for (int nt = 0; nt < 4; ++nt) {
        floatx4 acc = (floatx4){0.f, 0.f, 0.f, 0.f};
#pragma unroll
        for (int kt = 0; kt < 4; ++kt)
          acc = __builtin_amdgcn_mfma_f32_16x16x32_bf16(af[kt], xf[nt][kt], acc, 0, 0, 0);
        int node = row0 + nt * 16 + l16;
        if (node < Nn) {
          uint2 o;
          o.x = pk_bf16(acc[0] + bias.x, acc[1] + bias.y);
          o.y = pk_bf16(acc[2] + bias.z, acc[3] + bias.w);
          *(uint2*)&outp[(size_t)node * 64 + (wc >> 1)] = o;
        }
      }
    }
  } else {
    const int kb = 8 + (w - 1) * 4;    // k mtiles
    const int vb = 16 + (w - 1) * 4;   // v mtiles
#pragma unroll
    for (int i = 0; i < 4; ++i) {
      const int mk = kb + i, mv = vb + i;
      short8 afk[4], afv[4];
#pragma unroll
      for (int kt = 0; kt < 4; ++kt) {
        afk[kt] = *(const short8*)&WT[(size_t)(mk * 16 + l16) * 128 + kt * 32 + quad * 8];
        afv[kt] = *(const short8*)&WT[(size_t)(mv * 16 + l16) * 128 + kt * 32 + quad * 8];
      }
      float4 bk4 = *(const float4*)&bc[mk * 16 + quad * 4];
      float4 bv4 = *(const float4*)&bc[mv * 16 + quad * 4];
      const int krel = (w - 1) * 64 + i * 16 + quad * 4;   // col within k segment, 0..127
#pragma unroll
      for (int nt = 0; nt < 4; ++nt) {
        floatx4 ak = (floatx4){0.f, 0.f, 0.f, 0.f};
        floatx4 av = (floatx4){0.f, 0.f, 0.f, 0.f};
#pragma unroll
        for (int kt = 0; kt < 4; ++kt) {
          ak = __builtin_amdgcn_mfma_f32_16x16x32_bf16(afk[kt], xf[nt][kt], ak, 0, 0, 0);
          av = __builtin_amdgcn_mfma_f32_16x16x32_bf16(afv[kt], xf[nt][kt], av, 0, 0, 0);
        }
        int node = row0 + nt * 16 + l16;
        if (node < Nn) {
          // whole-dword packs: d0 = 4x k fp8, d1 = 4x v fp8
          int d0 = __builtin_amdgcn_cvt_pk_fp8_f32(ak[0] + bk4.x, ak[1] + bk4.y, 0, false);
          d0 = __builtin_amdgcn_cvt_pk_fp8_f32(ak[2] + bk4.z, ak[3] + bk4.w, d0, true);
          int d1 = __builtin_amdgcn_cvt_pk_fp8_f32(av[0] + bv4.x, av[1] + bv4.y, 0, false);
          d1 = __builtin_amdgcn_cvt_pk_fp8_f32(av[2] + bv4.z, av[3] + bv4.w, d1, true);
          uint2 o; o.x = (unsigned)d0; o.y = (unsigned)d1;
          *(uint2*)&kvp[(size_t)node * 64 + (krel >> 1)] = o;   // uint2-idx node*32 + krel/4
        }
      }
    }
  }
}

// ---------------- attention: one WAVE per node, 16 lanes per edge ----------------
// lane t16 = l&15 owns features 8t16..8t16+7; head = t16>>2 (4-lane groups).
// group g = l>>4 processes edge ebase+g; 4 edges per iteration, 2 chains.

__global__ __launch_bounds__(256)
void attn_kernel(unsigned int* __restrict__ q_h, const uint4* __restrict__ kvp4,
                 const uint4* __restrict__ xr4, const int* __restrict__ off,
                 const int* __restrict__ deg, const int* __restrict__ csr,
                 const float* __restrict__ Wb, int Nn) {
  int wv = __builtin_amdgcn_readfirstlane(threadIdx.x >> 6);
  int i = blockIdx.x * 4 + wv;
  if (i >= Nn) return;
  int l = threadIdx.x & 63;
  int t16 = l & 15;
  int g = l >> 4;

  // q features 8t16..+7, pre-scaled by 1/sqrt(32) * log2(e) for exp2 softmax
  const float QS = 0.17677669529663687f * 1.4426950408889634f;
  uint4 qw = ((const uint4*)q_h)[(size_t)i * 16 + t16];
  float q0 = bflo(qw.x) * QS, q1 = bfhi(qw.x) * QS;
  float q2 = bflo(qw.y) * QS, q3 = bfhi(qw.y) * QS;
  float q4 = bflo(qw.z) * QS, q5 = bfhi(qw.z) * QS;
  float q6 = bflo(qw.w) * QS, q7 = bfhi(qw.w) * QS;

  int e0 = off[i], e1 = e0 + deg[i];

  float denA = 0.f, denB = 0.f;
  float aA[8] = {0.f,0.f,0.f,0.f,0.f,0.f,0.f,0.f};
  float aB[8] = {0.f,0.f,0.f,0.f,0.f,0.f,0.f,0.f};

  auto body = [&](int e, float& den, float (&acc)[8]) {
    bool valid = e < e1;
    int ec = valid ? e : e1 - 1;
    int s = csr[ec];
    uint4 kv = kvp4[(size_t)s * 16 + t16];
    floatx2 k01 = __builtin_amdgcn_cvt_pk_f32_fp8((int)kv.x, false);
    floatx2 k23 = __builtin_amdgcn_cvt_pk_f32_fp8((int)kv.x, true);
    floatx2 k45 = __builtin_amdgcn_cvt_pk_f32_fp8((int)kv.z, false);
    floatx2 k67 = __builtin_amdgcn_cvt_pk_f32_fp8((int)kv.z, true);
    floatx2 v01 = __builtin_amdgcn_cvt_pk_f32_fp8((int)kv.y, false);
    floatx2 v23 = __builtin_amdgcn_cvt_pk_f32_fp8((int)kv.y, true);
    floatx2 v45 = __builtin_amdgcn_cvt_pk_f32_fp8((int)kv.w, false);
    floatx2 v67 = __builtin_amdgcn_cvt_pk_f32_fp8((int)kv.w, true);
    float d = q0 * k01.x + q1 * k01.y + q2 * k23.x + q3 * k23.y
            + q4 * k45.x + q5 * k45.y + q6 * k67.x + q7 * k67.y;
    d += __shfl_xor(d, 1);       // 4-lane (one head) reduce
    d += __shfl_xor(d, 2);
    float p = exp2f(d);
    p = valid ? p : 0.f;
    den += p;
    acc[0] += p * v01.x; acc[1] += p * v01.y;
    acc[2] += p * v23.x; acc[3] += p * v23.y;
    acc[4] += p * v45.x; acc[5] += p * v45.y;
    acc[6] += p * v67.x; acc[7] += p * v67.y;
  };

  int nIt = (e1 - e0 + 7) >> 3;   // wave-uniform (deg uniform per wave)
  int eA = e0 + g, eB = e0 + g + 4;
  for (int it = 0; it < nIt; ++it) {
    body(eA, denA, aA);
    body(eB, denB, aB);
    eA += 8; eB += 8;
  }

  // combine chains + 16-lane groups
  float den = denA + denB;
  den += __shfl_xor(den, 16);
  den += __shfl_xor(den, 32);
  float inv = 1.f / (den + 1e-16f);
  float o[8];
#pragma unroll
  for (int f = 0; f < 8; ++f) {
    float a = aA[f] + aB[f];
    a += __shfl_xor(a, 16);
    a += __shfl_xor(a, 32);
    o[f] = a * inv;
  }

  uint4 xw = xr4[(size_t)i * 16 + t16];
  float xr[8];
  xr[0] = bflo(xw.x); xr[1] = bfhi(xw.x);
  xr[2] = bflo(xw.y); xr[3] = bfhi(xw.y);
  xr[4] = bflo(xw.z); xr[5] = bfhi(xw.z);
  xr[6] = bflo(xw.w); xr[7] = bfhi(xw.w);

  // beta = sigmoid([o | xr | o-xr] . Wb)
  int f0 = t16 * 8;
  float4 wo0 = *(const float4*)&Wb[f0];
  float4 wo1 = *(const float4*)&Wb[f0 + 4];
  float4 wx0 = *(const float4*)&Wb[128 + f0];
  float4 wx1 = *(const float4*)&Wb[128 + f0 + 4];
  float4 wd0 = *(const float4*)&Wb[256 + f0];
  float4 wd1 = *(const float4*)&Wb[256 + f0 + 4];
  float c = o[0]*wo0.x + o[1]*wo0.y + o[2]*wo0.z + o[3]*wo0.w
          + o[4]*wo1.x + o[5]*wo1.y + o[6]*wo1.z + o[7]*wo1.w
          + xr[0]*wx0.x + xr[1]*wx0.y + xr[2]*wx0.z + xr[3]*wx0.w
          + xr[4]*wx1.x + xr[5]*wx1.y + xr[6]*wx1.z + xr[7]*wx1.w
          + (o[0]-xr[0])*wd0.x + (o[1]-xr[1])*wd0.y + (o[2]-xr[2])*wd0.z + (o[3]-xr[3])*wd0.w
          + (o[4]-xr[4])*wd1.x + (o[5]-xr[5])*wd1.y + (o[6]-xr[6])*wd1.z + (o[7]-xr[7])*wd1.w;
  c += __shfl_xor(c, 1);
  c += __shfl_xor(c, 2);
  c += __shfl_xor(c, 4);
  c += __shfl_xor(c, 8);
  float beta = 1.f / (1.f + __expf(-c));

  if (g == 0) {
    float h[8];
#pragma unroll
    for (int f = 0; f < 8; ++f) h[f] = fmaxf(beta * xr[f] + (1.f - beta) * o[f], 0.f);
    uint4 hw;
    hw.x = pk_bf16(h[0], h[1]); hw.y = pk_bf16(h[2], h[3]);
    hw.z = pk_bf16(h[4], h[5]); hw.w = pk_bf16(h[6], h[7]);
    ((uint4*)q_h)[(size_t)i * 16 + t16] = hw;
  }
}

// ---------------- fused mean-pool + MLP ----------------

__global__ __launch_bounds__(128)
void poolmlp_kernel(const unsigned short* __restrict__ h, const int* __restrict__ goff,
                    const int* __restrict__ gdeg,
                    const float* __restrict__ W1, const float* __restrict__ b1,
                    const float* __restrict__ W2, const float* __restrict__ b2,
                    const float* __restrict__ W3, const float* __restrict__ b3,
                    float* __restrict__ out) {
  int g = blockIdx.x;
  int t = threadIdx.x;
  int n0 = goff[g], cnt = gdeg[g];
  float s = 0.f;
  for (int n = n0; n < n0 + cnt; ++n) s += bflo(h[(size_t)n * 128 + t]);
  __shared__ float gv[128];
  __shared__ float t1[64];
  __shared__ float t2[32];
  gv[t] = s / fmaxf((float)cnt, 1.0f);
  __syncthreads();
  if (t < 64) {
    float a = b1[t];
    for (int k = 0; k < 128; ++k) a += gv[k] * W1[k * 64 + t];
    t1[t] = fmaxf(a, 0.f);
  }
  __syncthreads();
  if (t < 32) {
    float a = b2[t];
    for (int k = 0; k < 64; ++k) a += t1[k] * W2[k * 32 + t];
    t2[t] = fmaxf(a, 0.f);
  }
  __syncthreads();
  if (t == 0) {
    float a = b3[0];
    for (int k = 0; k < 32; ++k) a += t2[k] * W3[k];
    out[g] = 1.f / (1.f + __expf(-a));
  }
}

// ---------------- launch ----------------

extern "C" void kernel_launch(void* const* d_in, const int* in_sizes, int n_in,
                              void* d_out, int out_size, void* d_ws, size_t ws_size,
                              hipStream_t stream) {
  const float* x = (const float*)d_in[0];
  const int* edge_index = (const int*)d_in[1];
  const int* batch = (const int*)d_in[2];
  const int N = in_sizes[0] / DH;
  const int E = in_sizes[1] / 2;
  const int G = out_size;
  const int* src = edge_index;
  const int* dst = edge_index + E;

  const float* in_Wq = (const float*)d_in[3];
  const float* in_bq = (const float*)d_in[4];
  const float* in_Wk = (const float*)d_in[5];
  const float* in_bk = (const float*)d_in[6];
  const float* in_Wv = (const float*)d_in[7];
  const float* in_bv = (const float*)d_in[8];
  const float* in_Ws = (const float*)d_in[9];
  const float* in_bs = (const float*)d_in[10];
  const float* in_Wbeta = (const float*)d_in[11];
  const float* blk_Wq = (const float*)d_in[12];
  const float* blk_bq = (const float*)d_in[13];
  const float* blk_Wk = (const float*)d_in[14];
  const float* blk_bk = (const float*)d_in[15];
  const float* blk_Wv = (const float*)d_in[16];
  const float* blk_bv = (const float*)d_in[17];
  const float* blk_Ws = (const float*)d_in[18];
  const float* blk_bs = (const float*)d_in[19];
  const float* blk_Wbeta = (const float*)d_in[20];

  // workspace carve (256B aligned)
  char* p = (char*)d_ws;
  auto take = [&](size_t bytes) { char* r = p; p += (bytes + 255) & ~(size_t)255; return r; };
  __hip_bfloat16* h0 = (__hip_bfloat16*)take((size_t)N * DH * 2);
  __hip_bfloat16* h1 = (__hip_bfloat16*)take((size_t)N * DH * 2);
  unsigned char* kvp = (unsigned char*)take((size_t)N * 256);
  unsigned short* xr = (unsigned short*)take((size_t)N * DH * 2);
  __hip_bfloat16* WT = (__hip_bfloat16*)take((size_t)512 * DH * 2);
  float* bcat = (float*)take(512 * 4);
  int* deg    = (int*)take((size_t)N * 4);
  int* off    = (int*)take((size_t)N * 4);
  int* csr    = (int*)take((size_t)E * 4);
  int* part   = (int*)take((size_t)E * 4);
  int* hist   = (int*)take((size_t)NB * NBK * 4);
  int* total  = (int*)take(NBK * 4);
  int* tstart = (int*)take(NBK * 4);
  int* bsumP  = (int*)take(512 * 4);
  int* gdeg   = (int*)take((size_t)G * 4);
  int* goff   = (int*)take((size_t)G * 4);
  int* bsum2  = (int*)take(512 * 4);
  (void)n_in;
  if ((size_t)(p - (char*)d_ws) > ws_size) return;

  const int NBUCK = (N + 127) >> 7;
  const int chunk = (E + NB - 1) / NB;
  int nb = (N + 255) / 256;
  int gb = (G + 255) / 256;

  // ---- atomic-free CSR build ----
  csr_p1<<<NB, 256, 0, stream>>>(dst, hist, E, chunk);
  csr_p2<<<NBK / 256, 256, 0, stream>>>(hist, total);
  scan1_kernel<<<NBK / 256, 256, 0, stream>>>(total, tstart, bsumP, NBK);
  scan2_kernel<<<1, 512, 0, stream>>>(bsumP, NBK / 256);
  scan3_kernel<<<NBK / 256, 256, 0, stream>>>(tstart, bsumP, NBK);
  csr_p3<<<NB, 256, 0, stream>>>(src, dst, hist, tstart, part, E, chunk);
  csr_p4<<<NBUCK, 256, 0, stream>>>(part, tstart, total, deg, off, csr, N);

  // ---- graph segments (batch is sorted) ----
  zero_i32<<<gb, 256, 0, stream>>>(gdeg, G);
  hist_kernel<<<nb, 256, 0, stream>>>(batch, gdeg, N);
  scan1_kernel<<<gb, 256, 0, stream>>>(gdeg, goff, bsum2, G);
  scan2_kernel<<<1, 512, 0, stream>>>(bsum2, gb);
  scan3_kernel<<<gb, 256, 0, stream>>>(goff, bsum2, G);

  cvt_bf16<<<(int)(((size_t)N * DH + 255) / 256), 256, 0, stream>>>(x, h0, N * DH);

  for (int l = 0; l < 4; ++l) {
    const float *Wq, *Wk, *Wv, *Ws, *bq, *bk, *bv, *bs, *Wb;
    if (l == 0) {
      Wq = in_Wq; Wk = in_Wk; Wv = in_Wv; Ws = in_Ws;
      bq = in_bq; bk = in_bk; bv = in_bv; bs = in_bs; Wb = in_Wbeta;
    } else {
      int m = l - 1;
      Wq = blk_Wq + (size_t)m * DH * DH; Wk = blk_Wk + (size_t)m * DH * DH;
      Wv = blk_Wv + (size_t)m * DH * DH; Ws = blk_Ws + (size_t)m * DH * DH;
      bq = blk_bq + (size_t)m * DH; bk = blk_bk + (size_t)m * DH;
      bv = blk_bv + (size_t)m * DH; bs = blk_bs + (size_t)m * DH;
      Wb = blk_Wbeta + (size_t)m * 3 * DH;
    }
    __hip_bfloat16* hin  = (l & 1) ? h1 : h0;
    __hip_bfloat16* qbuf = (l & 1) ? h0 : h1;
    pack_w_kernel<<<(512 * DH + 255) / 256, 256, 0, stream>>>(Wq, Wk, Wv, Ws, bq, bk, bv, bs, WT, bcat);
    gemm_qkvs<<<(N + 63) / 64, 256, 0, stream>>>((const short*)hin, (const short*)WT, bcat,
        (unsigned int*)qbuf, (unsigned int*)kvp, (unsigned int*)xr, N);
    attn_kernel<<<(N + 3) / 4, 256, 0, stream>>>((unsigned int*)qbuf, (const uint4*)kvp,
        (const uint4*)xr, off, deg, csr, Wb, N);
  }

  // after 4 layers h lives in h0
  poolmlp_kernel<<<G, 128, 0, stream>>>((const unsigned short*)h0, goff, gdeg,
      (const float*)d_in[21], (const float*)d_in[22],
      (const float*)d_in[23], (const float*)d_in[24],
      (const float*)d_in[25], (const float*)d_in[26],
      (float*)d_out);
}

// Round 8
// 784.417 us; speedup vs baseline: 1.0546x; 1.0546x over previous
//
#include <hip/hip_runtime.h>
#include <hip/hip_bf16.h>
#include <cstdint>

#define DH 128   // hidden dim
#define NB 256   // partition blocks for CSR build
#define NBK 1024 // max buckets (N <= 131072)

typedef __attribute__((ext_vector_type(8))) short short8;
typedef __attribute__((ext_vector_type(4))) float floatx4;
typedef __attribute__((ext_vector_type(2))) float floatx2;

__device__ __forceinline__ float bflo(unsigned u) { return __uint_as_float(u << 16); }
__device__ __forceinline__ float bfhi(unsigned u) { return __uint_as_float(u & 0xffff0000u); }

__device__ __forceinline__ unsigned pk_bf16(float a, float b) {
  return ((unsigned)__bfloat16_as_ushort(__float2bfloat16(b)) << 16)
       | (unsigned)__bfloat16_as_ushort(__float2bfloat16(a));
}

template<int CTRL>
__device__ __forceinline__ float dpp_add(float x) {
  int y = __builtin_amdgcn_update_dpp(0, __float_as_int(x), CTRL, 0xf, 0xf, true);
  return x + __int_as_float(y);
}

// ---------------- fp32 -> bf16 convert ----------------

__global__ void cvt_bf16(const float* __restrict__ x, __hip_bfloat16* __restrict__ o, int n) {
  int i = blockIdx.x * 256 + threadIdx.x;
  if (i < n) o[i] = __float2bfloat16(x[i]);
}

// ---------------- scans (generic, for bucket starts) ----------------

__global__ void scan1_kernel(const int* __restrict__ deg, int* __restrict__ off,
                             int* __restrict__ bsum, int n) {
  __shared__ int sh[256];
  int idx = blockIdx.x * 256 + threadIdx.x;
  int v = (idx < n) ? deg[idx] : 0;
  sh[threadIdx.x] = v;
  __syncthreads();
  for (int d = 1; d < 256; d <<= 1) {
    int x = (threadIdx.x >= (unsigned)d) ? sh[threadIdx.x - d] : 0;
    __syncthreads();
    sh[threadIdx.x] += x;
    __syncthreads();
  }
  if (idx < n) off[idx] = sh[threadIdx.x] - v;   // exclusive
  if (threadIdx.x == 255) bsum[blockIdx.x] = sh[255];
}

__global__ void scan2_kernel(int* __restrict__ bsum, int nb) {
  __shared__ int sh[512];
  int t = threadIdx.x;
  int v = (t < nb) ? bsum[t] : 0;
  sh[t] = v;
  __syncthreads();
  for (int d = 1; d < 512; d <<= 1) {
    int x = (t >= (unsigned)d) ? sh[t - d] : 0;
    __syncthreads();
    sh[t] += x;
    __syncthreads();
  }
  if (t < nb) bsum[t] = sh[t] - v;
}

__global__ void scan3_kernel(int* __restrict__ off, const int* __restrict__ bsum, int n) {
  int idx = blockIdx.x * 256 + threadIdx.x;
  if (idx < n) off[idx] += bsum[blockIdx.x];
}

// ---------------- atomic-free CSR build (counting sort by dst>>7) ----------------
// hist layout TRANSPOSED: hist[bucket * NB + blk]

__global__ __launch_bounds__(256)
void csr_p1(const int* __restrict__ dst, int* __restrict__ hist, int E, int chunk) {
  __shared__ int cnt[NBK];
  const int blk = blockIdx.x, tid = threadIdx.x;
  for (int c = tid; c < NBK; c += 256) cnt[c] = 0;
  __syncthreads();
  int base = blk * chunk;
  int end = base + chunk; if (end > E) end = E;
  for (int e = base + tid; e < end; e += 256) atomicAdd(&cnt[dst[e] >> 7], 1);
  __syncthreads();
  for (int c = tid; c < NBK; c += 256) hist[c * NB + blk] = cnt[c];
}

// per-bucket exclusive prefix over blocks: one WAVE per bucket, coalesced int4 + shfl scan

__global__ __launch_bounds__(256)
void csr_p2(int* __restrict__ hist, int* __restrict__ total) {
  int b = blockIdx.x * 4 + (threadIdx.x >> 6);   // bucket
  int lane = threadIdx.x & 63;
  int4 v = *(int4*)&hist[b * NB + lane * 4];
  int s0 = v.x;
  int s1 = s0 + v.y;
  int s2 = s1 + v.z;
  int s3 = s2 + v.w;
  int t = s3;
  for (int d = 1; d < 64; d <<= 1) {
    int y = __shfl_up(t, d);
    if (lane >= d) t += y;
  }
  int excl = t - s3;
  int4 o;
  o.x = excl; o.y = excl + s0; o.z = excl + s1; o.w = excl + s2;
  *(int4*)&hist[b * NB + lane * 4] = o;
  if (lane == 63) total[b] = t;
}

__global__ __launch_bounds__(256)
void csr_p3(const int* __restrict__ src, const int* __restrict__ dst,
            const int* __restrict__ hist, const int* __restrict__ tstart,
            int* __restrict__ part, int E, int chunk) {
  __shared__ int cur[NBK];
  const int blk = blockIdx.x, tid = threadIdx.x;
  for (int c = tid; c < NBK; c += 256) cur[c] = hist[c * NB + blk] + tstart[c];
  __syncthreads();
  int base = blk * chunk;
  int end = base + chunk; if (end > E) end = E;
  for (int e = base + tid; e < end; e += 256) {
    int d = dst[e];
    int b = d >> 7;
    int pos = atomicAdd(&cur[b], 1);     // LDS atomic
    part[pos] = (src[e] << 7) | (d & 127);
  }
}

__global__ __launch_bounds__(256)
void csr_p4(const int* __restrict__ part, const int* __restrict__ tstart,
            const int* __restrict__ total, int* __restrict__ deg,
            int* __restrict__ off, int* __restrict__ csr, int Nn) {
  __shared__ int lcnt[128], lscan[128], lcur[128];
  const int b = blockIdx.x, tid = threadIdx.x;
  const int p0 = tstart[b];
  const int m = total[b];
  if (tid < 128) lcnt[tid] = 0;
  __syncthreads();
  for (int k = tid; k < m; k += 256) atomicAdd(&lcnt[part[p0 + k] & 127], 1);
  __syncthreads();
  if (tid < 128) lscan[tid] = lcnt[tid];
  __syncthreads();
  for (int d = 1; d < 128; d <<= 1) {
    int v = 0;
    if (tid < 128 && tid >= d) v = lscan[tid - d];
    __syncthreads();
    if (tid < 128) lscan[tid] += v;
    __syncthreads();
  }
  if (tid < 128) {
    int ex = lscan[tid] - lcnt[tid];
    lcur[tid] = ex;
    int n = (b << 7) + tid;
    if (n < Nn) { deg[n] = lcnt[tid]; off[n] = p0 + ex; }
  }
  __syncthreads();
  for (int k = tid; k < m; k += 256) {
    int pk = part[p0 + k];
    int pos = p0 + atomicAdd(&lcur[pk & 127], 1);   // LDS atomic
    csr[pos] = pk >> 7;
  }
}

// ---------------- graph segment offsets via binary search (batch sorted) --------

__global__ void goff_kernel(const int* __restrict__ batch, int* __restrict__ goff,
                            int N, int G) {
  int g = blockIdx.x * 256 + threadIdx.x;
  if (g > G) return;
  if (g == G) { goff[G] = N; return; }
  int lo = 0, hi = N;
  while (lo < hi) { int mid = (lo + hi) >> 1; if (batch[mid] < g) lo = mid + 1; else hi = mid; }
  goff[g] = lo;
}

// ---------------- weight pack: LDS-tiled transpose, coalesced both sides --------
// WT[c(512)][k(128)] bf16, c = which*128+cc. Blocks 0..63: 32x32 tiles; block 64: bias.

__global__ __launch_bounds__(256)
void pack_w_kernel(const float* __restrict__ Wq, const float* __restrict__ Wk,
                   const float* __restrict__ Wv, const float* __restrict__ Ws,
                   const float* __restrict__ bq, const float* __restrict__ bk,
                   const float* __restrict__ bv, const float* __restrict__ bs,
                   __hip_bfloat16* __restrict__ WT, float* __restrict__ bcat) {
  if (blockIdx.x == 64) {
    for (int c = threadIdx.x; c < 512; c += 256) {
      int which = c >> 7, cc = c & 127;
      const float* b = (which == 0) ? bq : (which == 1) ? bk : (which == 2) ? bv : bs;
      bcat[c] = b[cc];
    }
    return;
  }
  __shared__ float tile[32][33];
  const int bid = blockIdx.x;
  const int which = bid >> 4, kb = (bid >> 2) & 3, cb = bid & 3;
  const float* W = (which == 0) ? Wq : (which == 1) ? Wk : (which == 2) ? Wv : Ws;
  const int tx = threadIdx.x & 31, ty = threadIdx.x >> 5;   // ty 0..7
#pragma unroll
  for (int r = ty; r < 32; r += 8)
    tile[r][tx] = W[(kb * 32 + r) * 128 + cb * 32 + tx];
  __syncthreads();
#pragma unroll
  for (int r = ty; r < 32; r += 8)
    WT[(size_t)(which * 128 + cb * 32 + r) * 128 + kb * 32 + tx] = __float2bfloat16(tile[tx][r]);
}

// ---------------- fused QKVS GEMM (TRANSPOSED MFMA: D[wcol][node]) ----------------
// kvp dword f of node: {k(2f), k(2f+1), v(2f), v(2f+1)} fp8

__global__ __launch_bounds__(256)
void gemm_qkvs(const short* __restrict__ Xb, const short* __restrict__ WT,
               const float* __restrict__ bc,
               unsigned int* __restrict__ qout,
               unsigned int* __restrict__ kvp,
               unsigned int* __restrict__ xrout, int Nn) {
  const int row0 = blockIdx.x * 64;
  const int tid = threadIdx.x;
  const int w = tid >> 6, lane = tid & 63, quad = lane >> 4, l16 = lane & 15;

  // B-operand: X fragments, 4 node-tiles x 4 k-chunks (16B contiguous per lane)
  short8 xf[4][4];
#pragma unroll
  for (int nt = 0; nt < 4; ++nt) {
    int node = row0 + nt * 16 + l16; if (node >= Nn) node = Nn - 1;
#pragma unroll
    for (int kt = 0; kt < 4; ++kt)
      xf[nt][kt] = *(const short8*)&Xb[(size_t)node * 128 + kt * 32 + quad * 8];
  }

  if (w == 0 || w == 3) {
    unsigned int* outp = (w == 0) ? qout : xrout;
    const int mbase = (w == 0) ? 0 : 24;
#pragma unroll
    for (int i = 0; i < 8; ++i) {
      const int mt = mbase + i;
      short8 af[4];
#pragma unroll
      for (int kt = 0; kt < 4; ++kt)
        af[kt] = *(const short8*)&WT[(size_t)(mt * 16 + l16) * 128 + kt * 32 + quad * 8];
      float4 bias = *(const float4*)&bc[mt * 16 + quad * 4];
      const int wc = (i * 16 + quad * 4);   // col within 128-col segment
#pragma unroll
      for (int nt = 0; nt < 4; ++nt) {
        floatx4 acc = (floatx4){0.f, 0.f, 0.f, 0.f};
#pragma unroll
        for (int kt = 0; kt < 4; ++kt)
          acc = __builtin_amdgcn_mfma_f32_16x16x32_bf16(af[kt], xf[nt][kt], acc, 0, 0, 0);
        int node = row0 + nt * 16 + l16;
        if (node < Nn) {
          uint2 o;
          o.x = pk_bf16(acc[0] + bias.x, acc[1] + bias.y);
          o.y = pk_bf16(acc[2] + bias.z, acc[3] + bias.w);
          *(uint2*)&outp[(size_t)node * 64 + (wc >> 1)] = o;
        }
      }
    }
  } else {
    const int kb = 8 + (w - 1) * 4;    // k mtiles
    const int vb = 16 + (w - 1) * 4;   // v mtiles
#pragma unroll
    for (int i = 0; i < 4; ++i) {
      const int mk = kb + i, mv = vb + i;
      short8 afk[4], afv[4];
#pragma unroll
      for (int kt = 0; kt < 4; ++kt) {
        afk[kt] = *(const short8*)&WT[(size_t)(mk * 16 + l16) * 128 + kt * 32 + quad * 8];
        afv[kt] = *(const short8*)&WT[(size_t)(mv * 16 + l16) * 128 + kt * 32 + quad * 8];
      }
      float4 bk4 = *(const float4*)&bc[mk * 16 + quad * 4];
      float4 bv4 = *(const float4*)&bc[mv * 16 + quad * 4];
      const int krel = (w - 1) * 64 + i * 16 + quad * 4;   // col within k segment
#pragma unroll
      for (int nt = 0; nt < 4; ++nt) {
        floatx4 ak = (floatx4){0.f, 0.f, 0.f, 0.f};
        floatx4 av = (floatx4){0.f, 0.f, 0.f, 0.f};
#pragma unroll
        for (int kt = 0; kt < 4; ++kt) {
          ak = __builtin_amdgcn_mfma_f32_16x16x32_bf16(afk[kt], xf[nt][kt], ak, 0, 0, 0);
          av = __builtin_amdgcn_mfma_f32_16x16x32_bf16(afv[kt], xf[nt][kt], av, 0, 0, 0);
        }
        int node = row0 + nt * 16 + l16;
        if (node < Nn) {
          // dword pair: {k0,k1,v0,v1} then {k2,k3,v2,v3}
          int d0 = __builtin_amdgcn_cvt_pk_fp8_f32(ak[0] + bk4.x, ak[1] + bk4.y, 0, false);
          d0 = __builtin_amdgcn_cvt_pk_fp8_f32(av[0] + bv4.x, av[1] + bv4.y, d0, true);
          int d1 = __builtin_amdgcn_cvt_pk_fp8_f32(ak[2] + bk4.z, ak[3] + bk4.w, 0, false);
          d1 = __builtin_amdgcn_cvt_pk_fp8_f32(av[2] + bv4.z, av[3] + bv4.w, d1, true);
          uint2 o; o.x = (unsigned)d0; o.y = (unsigned)d1;
          *(uint2*)&kvp[(size_t)node * 64 + (krel >> 1)] = o;
        }
      }
    }
  }
}

// ---------------- attention: one WAVE per node, scalarized edge loop (R6) -------

__global__ __launch_bounds__(256)
void attn_kernel(unsigned int* __restrict__ q_h, const unsigned int* __restrict__ kvp,
                 const unsigned int* __restrict__ xrb, const int* __restrict__ off,
                 const int* __restrict__ deg, const int* __restrict__ csr,
                 const float* __restrict__ Wb, int Nn) {
  int wv = __builtin_amdgcn_readfirstlane(threadIdx.x >> 6);
  int i = blockIdx.x * 4 + wv;
  if (i >= Nn) return;
  int l = threadIdx.x & 63;

  unsigned qp = q_h[(size_t)i * 64 + l];
  float q0 = bflo(qp), q1 = bfhi(qp);
  int e0 = off[i], e1 = e0 + deg[i];

  float den0 = 0.f, x00 = 0.f, x10 = 0.f;
  float den1 = 0.f, x01 = 0.f, x11 = 0.f;
  float den2 = 0.f, x02 = 0.f, x12 = 0.f;
  float den3 = 0.f, x03 = 0.f, x13 = 0.f;

  auto body = [&](int e, float& den, float& a0, float& a1) {
    int s = csr[e];
    int kq = (int)kvp[(s << 6) | l];   // 32-bit address math (s*64 dwords + lane)
    floatx2 kk = __builtin_amdgcn_cvt_pk_f32_fp8(kq, false);   // bytes 0,1 = k0,k1
    floatx2 vv = __builtin_amdgcn_cvt_pk_f32_fp8(kq, true);    // bytes 2,3 = v0,v1
    float d = q0 * kk.x + q1 * kk.y;
    d = dpp_add<0x128>(d);   // row_ror:8
    d = dpp_add<0x124>(d);   // row_ror:4
    d = dpp_add<0x122>(d);   // row_ror:2
    d = dpp_add<0x121>(d);   // row_ror:1
    float p = __expf(d * 0.17677669529663687f);   // 1/sqrt(32)
    den += p; a0 += p * vv.x; a1 += p * vv.y;
  };

  int e = e0;
  for (; e + 3 < e1; e += 4) {
    body(e + 0, den0, x00, x10);
    body(e + 1, den1, x01, x11);
    body(e + 2, den2, x02, x12);
    body(e + 3, den3, x03, x13);
  }
  for (; e < e1; ++e) body(e, den0, x00, x10);

  float denom = den0 + den1 + den2 + den3 + 1e-16f;
  float o0 = (x00 + x01 + x02 + x03) / denom;
  float o1 = (x10 + x11 + x12 + x13) / denom;

  unsigned xp = xrb[(size_t)i * 64 + l];
  float xr0 = bflo(xp), xr1 = bfhi(xp);

  float c = o0 * Wb[2 * l] + o1 * Wb[2 * l + 1]
          + xr0 * Wb[128 + 2 * l] + xr1 * Wb[128 + 2 * l + 1]
          + (o0 - xr0) * Wb[256 + 2 * l] + (o1 - xr1) * Wb[256 + 2 * l + 1];
  c += __shfl_xor(c, 1);
  c += __shfl_xor(c, 2);
  c += __shfl_xor(c, 4);
  c += __shfl_xor(c, 8);
  c += __shfl_xor(c, 16);
  c += __shfl_xor(c, 32);
  float beta = 1.f / (1.f + __expf(-c));
  float h0 = fmaxf(beta * xr0 + (1.f - beta) * o0, 0.f);
  float h1 = fmaxf(beta * xr1 + (1.f - beta) * o1, 0.f);
  q_h[(size_t)i * 64 + l] = pk_bf16(h0, h1);
}

// ---------------- fused mean-pool + MLP ----------------

__global__ __launch_bounds__(128)
void poolmlp_kernel(const unsigned short* __restrict__ h, const int* __restrict__ goff,
                    const float* __restrict__ W1, const float* __restrict__ b1,
                    const float* __restrict__ W2, const float* __restrict__ b2,
                    const float* __restrict__ W3, const float* __restrict__ b3,
                    float* __restrict__ out) {
  int g = blockIdx.x;
  int t = threadIdx.x;
  int n0 = goff[g], cnt = goff[g + 1] - n0;
  float s = 0.f;
  for (int n = n0; n < n0 + cnt; ++n) s += bflo(h[(size_t)n * 128 + t]);
  __shared__ float gv[128];
  __shared__ float t1[64];
  __shared__ float t2[32];
  gv[t] = s / fmaxf((float)cnt, 1.0f);
  __syncthreads();
  if (t < 64) {
    float a = b1[t];
    for (int k = 0; k < 128; ++k) a += gv[k] * W1[k * 64 + t];
    t1[t] = fmaxf(a, 0.f);
  }
  __syncthreads();
  if (t < 32) {
    float a = b2[t];
    for (int k = 0; k < 64; ++k) a += t1[k] * W2[k * 32 + t];
    t2[t] = fmaxf(a, 0.f);
  }
  __syncthreads();
  if (t == 0) {
    float a = b3[0];
    for (int k = 0; k < 32; ++k) a += t2[k] * W3[k];
    out[g] = 1.f / (1.f + __expf(-a));
  }
}

// ---------------- launch ----------------

extern "C" void kernel_launch(void* const* d_in, const int* in_sizes, int n_in,
                              void* d_out, int out_size, void* d_ws, size_t ws_size,
                              hipStream_t stream) {
  const float* x = (const float*)d_in[0];
  const int* edge_index = (const int*)d_in[1];
  const int* batch = (const int*)d_in[2];
  const int N = in_sizes[0] / DH;
  const int E = in_sizes[1] / 2;
  const int G = out_size;
  const int* src = edge_index;
  const int* dst = edge_index + E;

  const float* in_Wq = (const float*)d_in[3];
  const float* in_bq = (const float*)d_in[4];
  const float* in_Wk = (const float*)d_in[5];
  const float* in_bk = (const float*)d_in[6];
  const float* in_Wv = (const float*)d_in[7];
  const float* in_bv = (const float*)d_in[8];
  const float* in_Ws = (const float*)d_in[9];
  const float* in_bs = (const float*)d_in[10];
  const float* in_Wbeta = (const float*)d_in[11];
  const float* blk_Wq = (const float*)d_in[12];
  const float* blk_bq = (const float*)d_in[13];
  const float* blk_Wk = (const float*)d_in[14];
  const float* blk_bk = (const float*)d_in[15];
  const float* blk_Wv = (const float*)d_in[16];
  const float* blk_bv = (const float*)d_in[17];
  const float* blk_Ws = (const float*)d_in[18];
  const float* blk_bs = (const float*)d_in[19];
  const float* blk_Wbeta = (const float*)d_in[20];

  // workspace carve (256B aligned)
  char* p = (char*)d_ws;
  auto take = [&](size_t bytes) { char* r = p; p += (bytes + 255) & ~(size_t)255; return r; };
  __hip_bfloat16* h0 = (__hip_bfloat16*)take((size_t)N * DH * 2);
  __hip_bfloat16* h1 = (__hip_bfloat16*)take((size_t)N * DH * 2);
  unsigned char* kvp = (unsigned char*)take((size_t)N * 256);
  unsigned short* xr = (unsigned short*)take((size_t)N * DH * 2);
  __hip_bfloat16* WT = (__hip_bfloat16*)take((size_t)512 * DH * 2);
  float* bcat = (float*)take(512 * 4);
  int* deg    = (int*)take((size_t)N * 4);
  int* off    = (int*)take((size_t)N * 4);
  int* csr    = (int*)take((size_t)E * 4);
  int* part   = (int*)take((size_t)E * 4);
  int* hist   = (int*)take((size_t)NB * NBK * 4);
  int* total  = (int*)take(NBK * 4);
  int* tstart = (int*)take(NBK * 4);
  int* bsumP  = (int*)take(512 * 4);
  int* goff   = (int*)take((size_t)(G + 1) * 4);
  (void)n_in;
  if ((size_t)(p - (char*)d_ws) > ws_size) return;

  const int NBUCK = (N + 127) >> 7;
  const int chunk = (E + NB - 1) / NB;

  // ---- atomic-free CSR build ----
  csr_p1<<<NB, 256, 0, stream>>>(dst, hist, E, chunk);
  csr_p2<<<NBK / 4, 256, 0, stream>>>(hist, total);
  scan1_kernel<<<NBK / 256, 256, 0, stream>>>(total, tstart, bsumP, NBK);
  scan2_kernel<<<1, 512, 0, stream>>>(bsumP, NBK / 256);
  scan3_kernel<<<NBK / 256, 256, 0, stream>>>(tstart, bsumP, NBK);
  csr_p3<<<NB, 256, 0, stream>>>(src, dst, hist, tstart, part, E, chunk);
  csr_p4<<<NBUCK, 256, 0, stream>>>(part, tstart, total, deg, off, csr, N);

  // ---- graph segment offsets (batch sorted) ----
  goff_kernel<<<(G + 256) / 256, 256, 0, stream>>>(batch, goff, N, G);

  cvt_bf16<<<(int)(((size_t)N * DH + 255) / 256), 256, 0, stream>>>(x, h0, N * DH);

  for (int l = 0; l < 4; ++l) {
    const float *Wq, *Wk, *Wv, *Ws, *bq, *bk, *bv, *bs, *Wb;
    if (l == 0) {
      Wq = in_Wq; Wk = in_Wk; Wv = in_Wv; Ws = in_Ws;
      bq = in_bq; bk = in_bk; bv = in_bv; bs = in_bs; Wb = in_Wbeta;
    } else {
      int m = l - 1;
      Wq = blk_Wq + (size_t)m * DH * DH; Wk = blk_Wk + (size_t)m * DH * DH;
      Wv = blk_Wv + (size_t)m * DH * DH; Ws = blk_Ws + (size_t)m * DH * DH;
      bq = blk_bq + (size_t)m * DH; bk = blk_bk + (size_t)m * DH;
      bv = blk_bv + (size_t)m * DH; bs = blk_bs + (size_t)m * DH;
      Wb = blk_Wbeta + (size_t)m * 3 * DH;
    }
    __hip_bfloat16* hin  = (l & 1) ? h1 : h0;
    __hip_bfloat16* qbuf = (l & 1) ? h0 : h1;
    pack_w_kernel<<<65, 256, 0, stream>>>(Wq, Wk, Wv, Ws, bq, bk, bv, bs, WT, bcat);
    gemm_qkvs<<<(N + 63) / 64, 256, 0, stream>>>((const short*)hin, (const short*)WT, bcat,
        (unsigned int*)qbuf, (unsigned int*)kvp, (unsigned int*)xr, N);
    attn_kernel<<<(N + 3) / 4, 256, 0, stream>>>((unsigned int*)qbuf, (const unsigned int*)kvp,
        (const unsigned int*)xr, off, deg, csr, Wb, N);
  }

  // after 4 layers h lives in h0
  poolmlp_kernel<<<G, 128, 0, stream>>>((const unsigned short*)h0, goff,
      (const float*)d_in[21], (const float*)d_in[22],
      (const float*)d_in[23], (const float*)d_in[24],
      (const float*)d_in[25], (const float*)d_in[26],
      (float*)d_out);
}

// Round 9
// 738.389 us; speedup vs baseline: 1.1204x; 1.0623x over previous
//
#include <hip/hip_runtime.h>
#include <hip/hip_bf16.h>
#include <cstdint>

#define DH 128   // hidden dim
#define NB 256   // partition blocks for CSR build
#define NBK 1024 // max buckets (N <= 131072)

typedef __attribute__((ext_vector_type(8))) short short8;
typedef __attribute__((ext_vector_type(4))) float floatx4;
typedef __attribute__((ext_vector_type(2))) float floatx2;

__device__ __forceinline__ float bflo(unsigned u) { return __uint_as_float(u << 16); }
__device__ __forceinline__ float bfhi(unsigned u) { return __uint_as_float(u & 0xffff0000u); }

__device__ __forceinline__ unsigned pk_bf16(float a, float b) {
  return ((unsigned)__bfloat16_as_ushort(__float2bfloat16(b)) << 16)
       | (unsigned)__bfloat16_as_ushort(__float2bfloat16(a));
}

template<int CTRL>
__device__ __forceinline__ float dpp_add(float x) {
  int y = __builtin_amdgcn_update_dpp(0, __float_as_int(x), CTRL, 0xf, 0xf, true);
  return x + __int_as_float(y);
}

// ---------------- fp32 -> bf16 convert ----------------

__global__ void cvt_bf16(const float* __restrict__ x, __hip_bfloat16* __restrict__ o, int n) {
  int i = blockIdx.x * 256 + threadIdx.x;
  if (i < n) o[i] = __float2bfloat16(x[i]);
}

// ---------------- scans (generic, for bucket starts) ----------------

__global__ void scan1_kernel(const int* __restrict__ deg, int* __restrict__ off,
                             int* __restrict__ bsum, int n) {
  __shared__ int sh[256];
  int idx = blockIdx.x * 256 + threadIdx.x;
  int v = (idx < n) ? deg[idx] : 0;
  sh[threadIdx.x] = v;
  __syncthreads();
  for (int d = 1; d < 256; d <<= 1) {
    int x = (threadIdx.x >= (unsigned)d) ? sh[threadIdx.x - d] : 0;
    __syncthreads();
    sh[threadIdx.x] += x;
    __syncthreads();
  }
  if (idx < n) off[idx] = sh[threadIdx.x] - v;   // exclusive
  if (threadIdx.x == 255) bsum[blockIdx.x] = sh[255];
}

__global__ void scan2_kernel(int* __restrict__ bsum, int nb) {
  __shared__ int sh[512];
  int t = threadIdx.x;
  int v = (t < nb) ? bsum[t] : 0;
  sh[t] = v;
  __syncthreads();
  for (int d = 1; d < 512; d <<= 1) {
    int x = (t >= (unsigned)d) ? sh[t - d] : 0;
    __syncthreads();
    sh[t] += x;
    __syncthreads();
  }
  if (t < nb) bsum[t] = sh[t] - v;
}

__global__ void scan3_kernel(int* __restrict__ off, const int* __restrict__ bsum, int n) {
  int idx = blockIdx.x * 256 + threadIdx.x;
  if (idx < n) off[idx] += bsum[blockIdx.x];
}

// ---------------- atomic-free CSR build (counting sort by dst>>7) ----------------
// hist layout TRANSPOSED: hist[bucket * NB + blk]

__global__ __launch_bounds__(256)
void csr_p1(const int* __restrict__ dst, int* __restrict__ hist, int E, int chunk) {
  __shared__ int cnt[NBK];
  const int blk = blockIdx.x, tid = threadIdx.x;
  for (int c = tid; c < NBK; c += 256) cnt[c] = 0;
  __syncthreads();
  int base = blk * chunk;
  int end = base + chunk; if (end > E) end = E;
  for (int e = base + tid; e < end; e += 256) atomicAdd(&cnt[dst[e] >> 7], 1);
  __syncthreads();
  for (int c = tid; c < NBK; c += 256) hist[c * NB + blk] = cnt[c];
}

// per-bucket exclusive prefix over blocks: one WAVE per bucket

__global__ __launch_bounds__(256)
void csr_p2(int* __restrict__ hist, int* __restrict__ total) {
  int b = blockIdx.x * 4 + (threadIdx.x >> 6);   // bucket
  int lane = threadIdx.x & 63;
  int4 v = *(int4*)&hist[b * NB + lane * 4];
  int s0 = v.x;
  int s1 = s0 + v.y;
  int s2 = s1 + v.z;
  int s3 = s2 + v.w;
  int t = s3;
  for (int d = 1; d < 64; d <<= 1) {
    int y = __shfl_up(t, d);
    if (lane >= d) t += y;
  }
  int excl = t - s3;
  int4 o;
  o.x = excl; o.y = excl + s0; o.z = excl + s1; o.w = excl + s2;
  *(int4*)&hist[b * NB + lane * 4] = o;
  if (lane == 63) total[b] = t;
}

__global__ __launch_bounds__(256)
void csr_p3(const int* __restrict__ src, const int* __restrict__ dst,
            const int* __restrict__ hist, const int* __restrict__ tstart,
            int* __restrict__ part, int E, int chunk) {
  __shared__ int cur[NBK];
  const int blk = blockIdx.x, tid = threadIdx.x;
  for (int c = tid; c < NBK; c += 256) cur[c] = hist[c * NB + blk] + tstart[c];
  __syncthreads();
  int base = blk * chunk;
  int end = base + chunk; if (end > E) end = E;
  for (int e = base + tid; e < end; e += 256) {
    int d = dst[e];
    int b = d >> 7;
    int pos = atomicAdd(&cur[b], 1);     // LDS atomic
    part[pos] = (src[e] << 7) | (d & 127);
  }
}

__global__ __launch_bounds__(256)
void csr_p4(const int* __restrict__ part, const int* __restrict__ tstart,
            const int* __restrict__ total, int* __restrict__ deg,
            int* __restrict__ off, int* __restrict__ csr, int Nn) {
  __shared__ int lcnt[128], lscan[128], lcur[128];
  const int b = blockIdx.x, tid = threadIdx.x;
  const int p0 = tstart[b];
  const int m = total[b];
  if (tid < 128) lcnt[tid] = 0;
  __syncthreads();
  for (int k = tid; k < m; k += 256) atomicAdd(&lcnt[part[p0 + k] & 127], 1);
  __syncthreads();
  if (tid < 128) lscan[tid] = lcnt[tid];
  __syncthreads();
  for (int d = 1; d < 128; d <<= 1) {
    int v = 0;
    if (tid < 128 && tid >= d) v = lscan[tid - d];
    __syncthreads();
    if (tid < 128) lscan[tid] += v;
    __syncthreads();
  }
  if (tid < 128) {
    int ex = lscan[tid] - lcnt[tid];
    lcur[tid] = ex;
    int n = (b << 7) + tid;
    if (n < Nn) { deg[n] = lcnt[tid]; off[n] = p0 + ex; }
  }
  __syncthreads();
  for (int k = tid; k < m; k += 256) {
    int pk = part[p0 + k];
    int pos = p0 + atomicAdd(&lcur[pk & 127], 1);   // LDS atomic
    csr[pos] = pk >> 7;
  }
}

// ---------------- graph segment offsets via binary search (batch sorted) --------

__global__ void goff_kernel(const int* __restrict__ batch, int* __restrict__ goff,
                            int N, int G) {
  int g = blockIdx.x * 256 + threadIdx.x;
  if (g > G) return;
  if (g == G) { goff[G] = N; return; }
  int lo = 0, hi = N;
  while (lo < hi) { int mid = (lo + hi) >> 1; if (batch[mid] < g) lo = mid + 1; else hi = mid; }
  goff[g] = lo;
}

// ---------------- weight pack -> MFMA FRAGMENT ORDER -----------------------------
// WT2 linear: (((mt*4 + kt)*16 + l16)*4 + quad)*8 + j  shorts,
// holding W element (c = mt*16+l16, k = kt*32+quad*8+j), c = which*128+cc.
// Per block: one 32x32 tile (which, kb=kt, cb); LDS transpose; coalesced both sides.

__global__ __launch_bounds__(256)
void pack_w_kernel(const float* __restrict__ Wq, const float* __restrict__ Wk,
                   const float* __restrict__ Wv, const float* __restrict__ Ws,
                   const float* __restrict__ bq, const float* __restrict__ bk,
                   const float* __restrict__ bv, const float* __restrict__ bs,
                   __hip_bfloat16* __restrict__ WT2, float* __restrict__ bcat) {
  if (blockIdx.x == 64) {
    for (int c = threadIdx.x; c < 512; c += 256) {
      int which = c >> 7, cc = c & 127;
      const float* b = (which == 0) ? bq : (which == 1) ? bk : (which == 2) ? bv : bs;
      bcat[c] = b[cc];
    }
    return;
  }
  __shared__ float tile[32][33];   // [k-row][c-col]
  const int bid = blockIdx.x;
  const int which = bid >> 4, kb = (bid >> 2) & 3, cb = bid & 3;
  const float* W = (which == 0) ? Wq : (which == 1) ? Wk : (which == 2) ? Wv : Ws;
  const int tx = threadIdx.x & 31, ty = threadIdx.x >> 5;   // ty 0..7
#pragma unroll
  for (int r = ty; r < 32; r += 8)
    tile[r][tx] = W[(kb * 32 + r) * 128 + cb * 32 + tx];
  __syncthreads();
  // write 4 consecutive j shorts per thread, fragment-order
  const int t = threadIdx.x;
  const int mt_sel = t >> 7;            // 0..1
  const int s4 = (t & 127) * 4;         // short offset within this mt's 512-short run
  const int l16 = s4 >> 5;              // 0..15
  const int quad = (s4 >> 3) & 3;       // 0..3
  const int j0 = s4 & 7;                // 0 or 4
  const int cl = mt_sel * 16 + l16;     // col within tile
  const int kr = quad * 8 + j0;         // k row within tile
  float f0 = tile[kr + 0][cl];
  float f1 = tile[kr + 1][cl];
  float f2 = tile[kr + 2][cl];
  float f3 = tile[kr + 3][cl];
  const int mt = which * 8 + cb * 2 + mt_sel;
  const int o = mt * 2048 + kb * 512 + l16 * 32 + quad * 8 + j0;   // shorts
  uint2 w;
  w.x = pk_bf16(f0, f1);
  w.y = pk_bf16(f2, f3);
  *(uint2*)&((unsigned short*)WT2)[o] = w;
}

// ---------------- fused QKVS GEMM (TRANSPOSED MFMA: D[wcol][node]) ----------------
// af loads from fragment-order WT2 (contiguous 1KB per wave-load);
// X staged in LDS once per block (coalesced), fragments via ds_read_b128.
// kvp dword f of node: {k(2f), k(2f+1), v(2f), v(2f+1)} fp8

__global__ __launch_bounds__(256)
void gemm_qkvs(const short* __restrict__ Xb, const short* __restrict__ WT2,
               const float* __restrict__ bc,
               unsigned int* __restrict__ qout,
               unsigned int* __restrict__ kvp,
               unsigned int* __restrict__ xrout, int Nn) {
  __shared__ short As[64][132];   // +4 pad -> frag ds_read stride 66 dwords (2-way, free)
  const int row0 = blockIdx.x * 64;
  const int tid = threadIdx.x;

  // stage X: 64 rows x 128 shorts = 1024 int4 chunks, fully coalesced
#pragma unroll
  for (int p = 0; p < 4; ++p) {
    int chunk = p * 256 + tid;
    int r = chunk >> 4, c8 = chunk & 15;
    int row = row0 + r; if (row >= Nn) row = Nn - 1;
    *(int4*)&As[r][c8 * 8] = *(const int4*)&Xb[(size_t)row * 128 + c8 * 8];
  }
  __syncthreads();

  const int w = tid >> 6, lane = tid & 63, quad = lane >> 4, l16 = lane & 15;

  // B-operand: X fragments from LDS
  short8 xf[4][4];
#pragma unroll
  for (int nt = 0; nt < 4; ++nt)
#pragma unroll
    for (int kt = 0; kt < 4; ++kt)
      xf[nt][kt] = *(const short8*)&As[nt * 16 + l16][kt * 32 + quad * 8];

  const int fbase = l16 * 32 + quad * 8;   // lane offset within a (mt,kt) 512-short frag run

  if (w == 0 || w == 3) {
    unsigned int* outp = (w == 0) ? qout : xrout;
    const int mbase = (w == 0) ? 0 : 24;
#pragma unroll
    for (int i = 0; i < 8; ++i) {
      const int mt = mbase + i;
      short8 af[4];
#pragma unroll
      for (int kt = 0; kt < 4; ++kt)
        af[kt] = *(const short8*)&WT2[mt * 2048 + kt * 512 + fbase];
      float4 bias = *(const float4*)&bc[mt * 16 + quad * 4];
      const int wc = (i * 16 + quad * 4);   // col within 128-col segment
#pragma unroll
      for (int nt = 0; nt < 4; ++nt) {
        floatx4 acc = (floatx4){0.f, 0.f, 0.f, 0.f};
#pragma unroll
        for (int kt = 0; kt < 4; ++kt)
          acc = __builtin_amdgcn_mfma_f32_16x16x32_bf16(af[kt], xf[nt][kt], acc, 0, 0, 0);
        int node = row0 + nt * 16 + l16;
        if (node < Nn) {
          uint2 o;
          o.x = pk_bf16(acc[0] + bias.x, acc[1] + bias.y);
          o.y = pk_bf16(acc[2] + bias.z, acc[3] + bias.w);
          *(uint2*)&outp[(size_t)node * 64 + (wc >> 1)] = o;
        }
      }
    }
  } else {
    const int kb = 8 + (w - 1) * 4;    // k mtiles
    const int vb = 16 + (w - 1) * 4;   // v mtiles
#pragma unroll
    for (int i = 0; i < 4; ++i) {
      const int mk = kb + i, mv = vb + i;
      short8 afk[4], afv[4];
#pragma unroll
      for (int kt = 0; kt < 4; ++kt) {
        afk[kt] = *(const short8*)&WT2[mk * 2048 + kt * 512 + fbase];
        afv[kt] = *(const short8*)&WT2[mv * 2048 + kt * 512 + fbase];
      }
      float4 bk4 = *(const float4*)&bc[mk * 16 + quad * 4];
      float4 bv4 = *(const float4*)&bc[mv * 16 + quad * 4];
      const int krel = (w - 1) * 64 + i * 16 + quad * 4;   // col within k segment
#pragma unroll
      for (int nt = 0; nt < 4; ++nt) {
        floatx4 ak = (floatx4){0.f, 0.f, 0.f, 0.f};
        floatx4 av = (floatx4){0.f, 0.f, 0.f, 0.f};
#pragma unroll
        for (int kt = 0; kt < 4; ++kt) {
          ak = __builtin_amdgcn_mfma_f32_16x16x32_bf16(afk[kt], xf[nt][kt], ak, 0, 0, 0);
          av = __builtin_amdgcn_mfma_f32_16x16x32_bf16(afv[kt], xf[nt][kt], av, 0, 0, 0);
        }
        int node = row0 + nt * 16 + l16;
        if (node < Nn) {
          // dword pair: {k0,k1,v0,v1} then {k2,k3,v2,v3}
          int d0 = __builtin_amdgcn_cvt_pk_fp8_f32(ak[0] + bk4.x, ak[1] + bk4.y, 0, false);
          d0 = __builtin_amdgcn_cvt_pk_fp8_f32(av[0] + bv4.x, av[1] + bv4.y, d0, true);
          int d1 = __builtin_amdgcn_cvt_pk_fp8_f32(ak[2] + bk4.z, ak[3] + bk4.w, 0, false);
          d1 = __builtin_amdgcn_cvt_pk_fp8_f32(av[2] + bv4.z, av[3] + bv4.w, d1, true);
          uint2 o; o.x = (unsigned)d0; o.y = (unsigned)d1;
          *(uint2*)&kvp[(size_t)node * 64 + (krel >> 1)] = o;
        }
      }
    }
  }
}

// ---------------- attention: one WAVE per node, scalarized edge loop (R6) -------

__global__ __launch_bounds__(256)
void attn_kernel(unsigned int* __restrict__ q_h, const unsigned int* __restrict__ kvp,
                 const unsigned int* __restrict__ xrb, const int* __restrict__ off,
                 const int* __restrict__ deg, const int* __restrict__ csr,
                 const float* __restrict__ Wb, int Nn) {
  int wv = __builtin_amdgcn_readfirstlane(threadIdx.x >> 6);
  int i = blockIdx.x * 4 + wv;
  if (i >= Nn) return;
  int l = threadIdx.x & 63;

  unsigned qp = q_h[(size_t)i * 64 + l];
  float q0 = bflo(qp), q1 = bfhi(qp);
  int e0 = off[i], e1 = e0 + deg[i];

  float den0 = 0.f, x00 = 0.f, x10 = 0.f;
  float den1 = 0.f, x01 = 0.f, x11 = 0.f;
  float den2 = 0.f, x02 = 0.f, x12 = 0.f;
  float den3 = 0.f, x03 = 0.f, x13 = 0.f;

  auto body = [&](int e, float& den, float& a0, float& a1) {
    int s = csr[e];
    int kq = (int)kvp[(s << 6) | l];   // 32-bit address math
    floatx2 kk = __builtin_amdgcn_cvt_pk_f32_fp8(kq, false);   // bytes 0,1 = k0,k1
    floatx2 vv = __builtin_amdgcn_cvt_pk_f32_fp8(kq, true);    // bytes 2,3 = v0,v1
    float d = q0 * kk.x + q1 * kk.y;
    d = dpp_add<0x128>(d);   // row_ror:8
    d = dpp_add<0x124>(d);   // row_ror:4
    d = dpp_add<0x122>(d);   // row_ror:2
    d = dpp_add<0x121>(d);   // row_ror:1
    float p = __expf(d * 0.17677669529663687f);   // 1/sqrt(32)
    den += p; a0 += p * vv.x; a1 += p * vv.y;
  };

  int e = e0;
  for (; e + 3 < e1; e += 4) {
    body(e + 0, den0, x00, x10);
    body(e + 1, den1, x01, x11);
    body(e + 2, den2, x02, x12);
    body(e + 3, den3, x03, x13);
  }
  for (; e < e1; ++e) body(e, den0, x00, x10);

  float denom = den0 + den1 + den2 + den3 + 1e-16f;
  float o0 = (x00 + x01 + x02 + x03) / denom;
  float o1 = (x10 + x11 + x12 + x13) / denom;

  unsigned xp = xrb[(size_t)i * 64 + l];
  float xr0 = bflo(xp), xr1 = bfhi(xp);

  float c = o0 * Wb[2 * l] + o1 * Wb[2 * l + 1]
          + xr0 * Wb[128 + 2 * l] + xr1 * Wb[128 + 2 * l + 1]
          + (o0 - xr0) * Wb[256 + 2 * l] + (o1 - xr1) * Wb[256 + 2 * l + 1];
  c += __shfl_xor(c, 1);
  c += __shfl_xor(c, 2);
  c += __shfl_xor(c, 4);
  c += __shfl_xor(c, 8);
  c += __shfl_xor(c, 16);
  c += __shfl_xor(c, 32);
  float beta = 1.f / (1.f + __expf(-c));
  float h0 = fmaxf(beta * xr0 + (1.f - beta) * o0, 0.f);
  float h1 = fmaxf(beta * xr1 + (1.f - beta) * o1, 0.f);
  q_h[(size_t)i * 64 + l] = pk_bf16(h0, h1);
}

// ---------------- fused mean-pool + MLP ----------------

__global__ __launch_bounds__(128)
void poolmlp_kernel(const unsigned short* __restrict__ h, const int* __restrict__ goff,
                    const float* __restrict__ W1, const float* __restrict__ b1,
                    const float* __restrict__ W2, const float* __restrict__ b2,
                    const float* __restrict__ W3, const float* __restrict__ b3,
                    float* __restrict__ out) {
  int g = blockIdx.x;
  int t = threadIdx.x;
  int n0 = goff[g], cnt = goff[g + 1] - n0;
  float s = 0.f;
  for (int n = n0; n < n0 + cnt; ++n) s += bflo(h[(size_t)n * 128 + t]);
  __shared__ float gv[128];
  __shared__ float t1[64];
  __shared__ float t2[32];
  gv[t] = s / fmaxf((float)cnt, 1.0f);
  __syncthreads();
  if (t < 64) {
    float a = b1[t];
    for (int k = 0; k < 128; ++k) a += gv[k] * W1[k * 64 + t];
    t1[t] = fmaxf(a, 0.f);
  }
  __syncthreads();
  if (t < 32) {
    float a = b2[t];
    for (int k = 0; k < 64; ++k) a += t1[k] * W2[k * 32 + t];
    t2[t] = fmaxf(a, 0.f);
  }
  __syncthreads();
  if (t == 0) {
    float a = b3[0];
    for (int k = 0; k < 32; ++k) a += t2[k] * W3[k];
    out[g] = 1.f / (1.f + __expf(-a));
  }
}

// ---------------- launch ----------------

extern "C" void kernel_launch(void* const* d_in, const int* in_sizes, int n_in,
                              void* d_out, int out_size, void* d_ws, size_t ws_size,
                              hipStream_t stream) {
  const float* x = (const float*)d_in[0];
  const int* edge_index = (const int*)d_in[1];
  const int* batch = (const int*)d_in[2];
  const int N = in_sizes[0] / DH;
  const int E = in_sizes[1] / 2;
  const int G = out_size;
  const int* src = edge_index;
  const int* dst = edge_index + E;

  const float* in_Wq = (const float*)d_in[3];
  const float* in_bq = (const float*)d_in[4];
  const float* in_Wk = (const float*)d_in[5];
  const float* in_bk = (const float*)d_in[6];
  const float* in_Wv = (const float*)d_in[7];
  const float* in_bv = (const float*)d_in[8];
  const float* in_Ws = (const float*)d_in[9];
  const float* in_bs = (const float*)d_in[10];
  const float* in_Wbeta = (const float*)d_in[11];
  const float* blk_Wq = (const float*)d_in[12];
  const float* blk_bq = (const float*)d_in[13];
  const float* blk_Wk = (const float*)d_in[14];
  const float* blk_bk = (const float*)d_in[15];
  const float* blk_Wv = (const float*)d_in[16];
  const float* blk_bv = (const float*)d_in[17];
  const float* blk_Ws = (const float*)d_in[18];
  const float* blk_bs = (const float*)d_in[19];
  const float* blk_Wbeta = (const float*)d_in[20];

  // workspace carve (256B aligned)
  char* p = (char*)d_ws;
  auto take = [&](size_t bytes) { char* r = p; p += (bytes + 255) & ~(size_t)255; return r; };
  __hip_bfloat16* h0 = (__hip_bfloat16*)take((size_t)N * DH * 2);
  __hip_bfloat16* h1 = (__hip_bfloat16*)take((size_t)N * DH * 2);
  unsigned char* kvp = (unsigned char*)take((size_t)N * 256);
  unsigned short* xr = (unsigned short*)take((size_t)N * DH * 2);
  __hip_bfloat16* WT2 = (__hip_bfloat16*)take((size_t)512 * DH * 2);
  float* bcat = (float*)take(512 * 4);
  int* deg    = (int*)take((size_t)N * 4);
  int* off    = (int*)take((size_t)N * 4);
  int* csr    = (int*)take((size_t)E * 4);
  int* part   = (int*)take((size_t)E * 4);
  int* hist   = (int*)take((size_t)NB * NBK * 4);
  int* total  = (int*)take(NBK * 4);
  int* tstart = (int*)take(NBK * 4);
  int* bsumP  = (int*)take(512 * 4);
  int* goff   = (int*)take((size_t)(G + 1) * 4);
  (void)n_in;
  if ((size_t)(p - (char*)d_ws) > ws_size) return;

  const int NBUCK = (N + 127) >> 7;
  const int chunk = (E + NB - 1) / NB;

  // ---- atomic-free CSR build ----
  csr_p1<<<NB, 256, 0, stream>>>(dst, hist, E, chunk);
  csr_p2<<<NBK / 4, 256, 0, stream>>>(hist, total);
  scan1_kernel<<<NBK / 256, 256, 0, stream>>>(total, tstart, bsumP, NBK);
  scan2_kernel<<<1, 512, 0, stream>>>(bsumP, NBK / 256);
  scan3_kernel<<<NBK / 256, 256, 0, stream>>>(tstart, bsumP, NBK);
  csr_p3<<<NB, 256, 0, stream>>>(src, dst, hist, tstart, part, E, chunk);
  csr_p4<<<NBUCK, 256, 0, stream>>>(part, tstart, total, deg, off, csr, N);

  // ---- graph segment offsets (batch sorted) ----
  goff_kernel<<<(G + 256) / 256, 256, 0, stream>>>(batch, goff, N, G);

  cvt_bf16<<<(int)(((size_t)N * DH + 255) / 256), 256, 0, stream>>>(x, h0, N * DH);

  for (int l = 0; l < 4; ++l) {
    const float *Wq, *Wk, *Wv, *Ws, *bq, *bk, *bv, *bs, *Wb;
    if (l == 0) {
      Wq = in_Wq; Wk = in_Wk; Wv = in_Wv; Ws = in_Ws;
      bq = in_bq; bk = in_bk; bv = in_bv; bs = in_bs; Wb = in_Wbeta;
    } else {
      int m = l - 1;
      Wq = blk_Wq + (size_t)m * DH * DH; Wk = blk_Wk + (size_t)m * DH * DH;
      Wv = blk_Wv + (size_t)m * DH * DH; Ws = blk_Ws + (size_t)m * DH * DH;
      bq = blk_bq + (size_t)m * DH; bk = blk_bk + (size_t)m * DH;
      bv = blk_bv + (size_t)m * DH; bs = blk_bs + (size_t)m * DH;
      Wb = blk_Wbeta + (size_t)m * 3 * DH;
    }
    __hip_bfloat16* hin  = (l & 1) ? h1 : h0;
    __hip_bfloat16* qbuf = (l & 1) ? h0 : h1;
    pack_w_kernel<<<65, 256, 0, stream>>>(Wq, Wk, Wv, Ws, bq, bk, bv, bs, WT2, bcat);
    gemm_qkvs<<<(N + 63) / 64, 256, 0, stream>>>((const short*)hin, (const short*)WT2, bcat,
        (unsigned int*)qbuf, (unsigned int*)kvp, (unsigned int*)xr, N);
    attn_kernel<<<(N + 3) / 4, 256, 0, stream>>>((unsigned int*)qbuf, (const unsigned int*)kvp,
        (const unsigned int*)xr, off, deg, csr, Wb, N);
  }

  // after 4 layers h lives in h0
  poolmlp_kernel<<<G, 128, 0, stream>>>((const unsigned short*)h0, goff,
      (const float*)d_in[21], (const float*)d_in[22],
      (const float*)d_in[23], (const float*)d_in[24],
      (const float*)d_in[25], (const float*)d_in[26],
      (float*)d_out);
}

// Round 10
// 725.561 us; speedup vs baseline: 1.1402x; 1.0177x over previous
//
#include <hip/hip_runtime.h>
#include <hip/hip_bf16.h>
#include <cstdint>

#define DH 128   // hidden dim
#define NB 256   // partition blocks for CSR build
#define NBK 1024 // max buckets (N <= 131072)

typedef __attribute__((ext_vector_type(8))) short short8;
typedef __attribute__((ext_vector_type(4))) float floatx4;
typedef __attribute__((ext_vector_type(2))) float floatx2;

__device__ __forceinline__ float bflo(unsigned u) { return __uint_as_float(u << 16); }
__device__ __forceinline__ float bfhi(unsigned u) { return __uint_as_float(u & 0xffff0000u); }

__device__ __forceinline__ unsigned pk_bf16(float a, float b) {
  return ((unsigned)__bfloat16_as_ushort(__float2bfloat16(b)) << 16)
       | (unsigned)__bfloat16_as_ushort(__float2bfloat16(a));
}

template<int CTRL>
__device__ __forceinline__ float dpp_add(float x) {
  int y = __builtin_amdgcn_update_dpp(0, __float_as_int(x), CTRL, 0xf, 0xf, true);
  return x + __int_as_float(y);
}

// ---------------- fp32 -> bf16 convert ----------------

__global__ void cvt_bf16(const float* __restrict__ x, __hip_bfloat16* __restrict__ o, int n) {
  int i = blockIdx.x * 256 + threadIdx.x;
  if (i < n) o[i] = __float2bfloat16(x[i]);
}

// ---------------- scans (generic, for bucket starts) ----------------

__global__ void scan1_kernel(const int* __restrict__ deg, int* __restrict__ off,
                             int* __restrict__ bsum, int n) {
  __shared__ int sh[256];
  int idx = blockIdx.x * 256 + threadIdx.x;
  int v = (idx < n) ? deg[idx] : 0;
  sh[threadIdx.x] = v;
  __syncthreads();
  for (int d = 1; d < 256; d <<= 1) {
    int x = (threadIdx.x >= (unsigned)d) ? sh[threadIdx.x - d] : 0;
    __syncthreads();
    sh[threadIdx.x] += x;
    __syncthreads();
  }
  if (idx < n) off[idx] = sh[threadIdx.x] - v;   // exclusive
  if (threadIdx.x == 255) bsum[blockIdx.x] = sh[255];
}

__global__ void scan2_kernel(int* __restrict__ bsum, int nb) {
  __shared__ int sh[512];
  int t = threadIdx.x;
  int v = (t < nb) ? bsum[t] : 0;
  sh[t] = v;
  __syncthreads();
  for (int d = 1; d < 512; d <<= 1) {
    int x = (t >= (unsigned)d) ? sh[t - d] : 0;
    __syncthreads();
    sh[t] += x;
    __syncthreads();
  }
  if (t < nb) bsum[t] = sh[t] - v;
}

__global__ void scan3_kernel(int* __restrict__ off, const int* __restrict__ bsum, int n) {
  int idx = blockIdx.x * 256 + threadIdx.x;
  if (idx < n) off[idx] += bsum[blockIdx.x];
}

// ---------------- atomic-free CSR build (counting sort by dst>>7) ----------------
// hist layout TRANSPOSED: hist[bucket * NB + blk]

__global__ __launch_bounds__(256)
void csr_p1(const int* __restrict__ dst, int* __restrict__ hist, int E, int chunk) {
  __shared__ int cnt[NBK];
  const int blk = blockIdx.x, tid = threadIdx.x;
  for (int c = tid; c < NBK; c += 256) cnt[c] = 0;
  __syncthreads();
  int base = blk * chunk;
  int end = base + chunk; if (end > E) end = E;
  for (int e = base + tid; e < end; e += 256) atomicAdd(&cnt[dst[e] >> 7], 1);
  __syncthreads();
  for (int c = tid; c < NBK; c += 256) hist[c * NB + blk] = cnt[c];
}

// per-bucket exclusive prefix over blocks: one WAVE per bucket

__global__ __launch_bounds__(256)
void csr_p2(int* __restrict__ hist, int* __restrict__ total) {
  int b = blockIdx.x * 4 + (threadIdx.x >> 6);   // bucket
  int lane = threadIdx.x & 63;
  int4 v = *(int4*)&hist[b * NB + lane * 4];
  int s0 = v.x;
  int s1 = s0 + v.y;
  int s2 = s1 + v.z;
  int s3 = s2 + v.w;
  int t = s3;
  for (int d = 1; d < 64; d <<= 1) {
    int y = __shfl_up(t, d);
    if (lane >= d) t += y;
  }
  int excl = t - s3;
  int4 o;
  o.x = excl; o.y = excl + s0; o.z = excl + s1; o.w = excl + s2;
  *(int4*)&hist[b * NB + lane * 4] = o;
  if (lane == 63) total[b] = t;
}

__global__ __launch_bounds__(256)
void csr_p3(const int* __restrict__ src, const int* __restrict__ dst,
            const int* __restrict__ hist, const int* __restrict__ tstart,
            int* __restrict__ part, int E, int chunk) {
  __shared__ int cur[NBK];
  const int blk = blockIdx.x, tid = threadIdx.x;
  for (int c = tid; c < NBK; c += 256) cur[c] = hist[c * NB + blk] + tstart[c];
  __syncthreads();
  int base = blk * chunk;
  int end = base + chunk; if (end > E) end = E;
  for (int e = base + tid; e < end; e += 256) {
    int d = dst[e];
    int b = d >> 7;
    int pos = atomicAdd(&cur[b], 1);     // LDS atomic
    part[pos] = (src[e] << 7) | (d & 127);
  }
}

__global__ __launch_bounds__(256)
void csr_p4(const int* __restrict__ part, const int* __restrict__ tstart,
            const int* __restrict__ total, int* __restrict__ deg,
            int* __restrict__ off, int* __restrict__ csr, int Nn) {
  __shared__ int lcnt[128], lscan[128], lcur[128];
  const int b = blockIdx.x, tid = threadIdx.x;
  const int p0 = tstart[b];
  const int m = total[b];
  if (tid < 128) lcnt[tid] = 0;
  __syncthreads();
  for (int k = tid; k < m; k += 256) atomicAdd(&lcnt[part[p0 + k] & 127], 1);
  __syncthreads();
  if (tid < 128) lscan[tid] = lcnt[tid];
  __syncthreads();
  for (int d = 1; d < 128; d <<= 1) {
    int v = 0;
    if (tid < 128 && tid >= d) v = lscan[tid - d];
    __syncthreads();
    if (tid < 128) lscan[tid] += v;
    __syncthreads();
  }
  if (tid < 128) {
    int ex = lscan[tid] - lcnt[tid];
    lcur[tid] = ex;
    int n = (b << 7) + tid;
    if (n < Nn) { deg[n] = lcnt[tid]; off[n] = p0 + ex; }
  }
  __syncthreads();
  for (int k = tid; k < m; k += 256) {
    int pk = part[p0 + k];
    int pos = p0 + atomicAdd(&lcur[pk & 127], 1);   // LDS atomic
    csr[pos] = pk >> 7;
  }
}

// ---------------- graph segment offsets via binary search (batch sorted) --------

__global__ void goff_kernel(const int* __restrict__ batch, int* __restrict__ goff,
                            int N, int G) {
  int g = blockIdx.x * 256 + threadIdx.x;
  if (g > G) return;
  if (g == G) { goff[G] = N; return; }
  int lo = 0, hi = N;
  while (lo < hi) { int mid = (lo + hi) >> 1; if (batch[mid] < g) lo = mid + 1; else hi = mid; }
  goff[g] = lo;
}

// ---------------- weight pack -> MFMA FRAGMENT ORDER -----------------------------

__global__ __launch_bounds__(256)
void pack_w_kernel(const float* __restrict__ Wq, const float* __restrict__ Wk,
                   const float* __restrict__ Wv, const float* __restrict__ Ws,
                   const float* __restrict__ bq, const float* __restrict__ bk,
                   const float* __restrict__ bv, const float* __restrict__ bs,
                   __hip_bfloat16* __restrict__ WT2, float* __restrict__ bcat) {
  if (blockIdx.x == 64) {
    for (int c = threadIdx.x; c < 512; c += 256) {
      int which = c >> 7, cc = c & 127;
      const float* b = (which == 0) ? bq : (which == 1) ? bk : (which == 2) ? bv : bs;
      bcat[c] = b[cc];
    }
    return;
  }
  __shared__ float tile[32][33];   // [k-row][c-col]
  const int bid = blockIdx.x;
  const int which = bid >> 4, kb = (bid >> 2) & 3, cb = bid & 3;
  const float* W = (which == 0) ? Wq : (which == 1) ? Wk : (which == 2) ? Wv : Ws;
  const int tx = threadIdx.x & 31, ty = threadIdx.x >> 5;   // ty 0..7
#pragma unroll
  for (int r = ty; r < 32; r += 8)
    tile[r][tx] = W[(kb * 32 + r) * 128 + cb * 32 + tx];
  __syncthreads();
  const int t = threadIdx.x;
  const int mt_sel = t >> 7;            // 0..1
  const int s4 = (t & 127) * 4;         // short offset within this mt's 512-short run
  const int l16 = s4 >> 5;              // 0..15
  const int quad = (s4 >> 3) & 3;       // 0..3
  const int j0 = s4 & 7;                // 0 or 4
  const int cl = mt_sel * 16 + l16;     // col within tile
  const int kr = quad * 8 + j0;         // k row within tile
  float f0 = tile[kr + 0][cl];
  float f1 = tile[kr + 1][cl];
  float f2 = tile[kr + 2][cl];
  float f3 = tile[kr + 3][cl];
  const int mt = which * 8 + cb * 2 + mt_sel;
  const int o = mt * 2048 + kb * 512 + l16 * 32 + quad * 8 + j0;   // shorts
  uint2 w;
  w.x = pk_bf16(f0, f1);
  w.y = pk_bf16(f2, f3);
  *(uint2*)&((unsigned short*)WT2)[o] = w;
}

// ---------------- fused QKVS GEMM (TRANSPOSED MFMA: D[wcol][node]) ----------------
// kvp dword f of node: {k(2f), k(2f+1), v(2f), v(2f+1)} fp8

__global__ __launch_bounds__(256)
void gemm_qkvs(const short* __restrict__ Xb, const short* __restrict__ WT2,
               const float* __restrict__ bc,
               unsigned int* __restrict__ qout,
               unsigned int* __restrict__ kvp,
               unsigned int* __restrict__ xrout, int Nn) {
  __shared__ short As[64][132];   // +4 pad
  const int row0 = blockIdx.x * 64;
  const int tid = threadIdx.x;

#pragma unroll
  for (int p = 0; p < 4; ++p) {
    int chunk = p * 256 + tid;
    int r = chunk >> 4, c8 = chunk & 15;
    int row = row0 + r; if (row >= Nn) row = Nn - 1;
    *(int4*)&As[r][c8 * 8] = *(const int4*)&Xb[(size_t)row * 128 + c8 * 8];
  }
  __syncthreads();

  const int w = tid >> 6, lane = tid & 63, quad = lane >> 4, l16 = lane & 15;

  short8 xf[4][4];
#pragma unroll
  for (int nt = 0; nt < 4; ++nt)
#pragma unroll
    for (int kt = 0; kt < 4; ++kt)
      xf[nt][kt] = *(const short8*)&As[nt * 16 + l16][kt * 32 + quad * 8];

  const int fbase = l16 * 32 + quad * 8;

  if (w == 0 || w == 3) {
    unsigned int* outp = (w == 0) ? qout : xrout;
    const int mbase = (w == 0) ? 0 : 24;
#pragma unroll
    for (int i = 0; i < 8; ++i) {
      const int mt = mbase + i;
      short8 af[4];
#pragma unroll
      for (int kt = 0; kt < 4; ++kt)
        af[kt] = *(const short8*)&WT2[mt * 2048 + kt * 512 + fbase];
      float4 bias = *(const float4*)&bc[mt * 16 + quad * 4];
      const int wc = (i * 16 + quad * 4);
#pragma unroll
      for (int nt = 0; nt < 4; ++nt) {
        floatx4 acc = (floatx4){0.f, 0.f, 0.f, 0.f};
#pragma unroll
        for (int kt = 0; kt < 4; ++kt)
          acc = __builtin_amdgcn_mfma_f32_16x16x32_bf16(af[kt], xf[nt][kt], acc, 0, 0, 0);
        int node = row0 + nt * 16 + l16;
        if (node < Nn) {
          uint2 o;
          o.x = pk_bf16(acc[0] + bias.x, acc[1] + bias.y);
          o.y = pk_bf16(acc[2] + bias.z, acc[3] + bias.w);
          *(uint2*)&outp[(size_t)node * 64 + (wc >> 1)] = o;
        }
      }
    }
  } else {
    const int kb = 8 + (w - 1) * 4;
    const int vb = 16 + (w - 1) * 4;
#pragma unroll
    for (int i = 0; i < 4; ++i) {
      const int mk = kb + i, mv = vb + i;
      short8 afk[4], afv[4];
#pragma unroll
      for (int kt = 0; kt < 4; ++kt) {
        afk[kt] = *(const short8*)&WT2[mk * 2048 + kt * 512 + fbase];
        afv[kt] = *(const short8*)&WT2[mv * 2048 + kt * 512 + fbase];
      }
      float4 bk4 = *(const float4*)&bc[mk * 16 + quad * 4];
      float4 bv4 = *(const float4*)&bc[mv * 16 + quad * 4];
      const int krel = (w - 1) * 64 + i * 16 + quad * 4;
#pragma unroll
      for (int nt = 0; nt < 4; ++nt) {
        floatx4 ak = (floatx4){0.f, 0.f, 0.f, 0.f};
        floatx4 av = (floatx4){0.f, 0.f, 0.f, 0.f};
#pragma unroll
        for (int kt = 0; kt < 4; ++kt) {
          ak = __builtin_amdgcn_mfma_f32_16x16x32_bf16(afk[kt], xf[nt][kt], ak, 0, 0, 0);
          av = __builtin_amdgcn_mfma_f32_16x16x32_bf16(afv[kt], xf[nt][kt], av, 0, 0, 0);
        }
        int node = row0 + nt * 16 + l16;
        if (node < Nn) {
          int d0 = __builtin_amdgcn_cvt_pk_fp8_f32(ak[0] + bk4.x, ak[1] + bk4.y, 0, false);
          d0 = __builtin_amdgcn_cvt_pk_fp8_f32(av[0] + bv4.x, av[1] + bv4.y, d0, true);
          int d1 = __builtin_amdgcn_cvt_pk_fp8_f32(ak[2] + bk4.z, ak[3] + bk4.w, 0, false);
          d1 = __builtin_amdgcn_cvt_pk_fp8_f32(av[2] + bv4.z, av[3] + bv4.w, d1, true);
          uint2 o; o.x = (unsigned)d0; o.y = (unsigned)d1;
          *(uint2*)&kvp[(size_t)node * 64 + (krel >> 1)] = o;
        }
      }
    }
  }
}

// ---------------- attention: one WAVE per node, 32 lanes per edge ----------------
// lane l: j = l&31 owns features 4j..4j+3; head = j>>3 (8-lane groups);
// g = l>>5 selects edge slot. 2 edges per iteration, 2 chains (4 in flight).
// csr reads stay SCALAR (wave-uniform e); per-lane node id via cndmask.
// q pre-scaled by 1/sqrt(32)*log2(e) -> bare v_exp per 2 edges.

__global__ __launch_bounds__(256)
void attn_kernel(unsigned int* __restrict__ q_h, const uint2* __restrict__ kvp2,
                 const uint2* __restrict__ xr2, const int* __restrict__ off,
                 const int* __restrict__ deg, const int* __restrict__ csr,
                 const float* __restrict__ Wb, int Nn) {
  int wv = __builtin_amdgcn_readfirstlane(threadIdx.x >> 6);
  int i = blockIdx.x * 4 + wv;
  if (i >= Nn) return;
  const int l = threadIdx.x & 63;
  const int j = l & 31;
  const int g = l >> 5;

  const float QS = 0.17677669529663687f * 1.4426950408889634f;  // 1/sqrt(32)*log2e
  uint2 qw = ((const uint2*)q_h)[(size_t)i * 32 + j];
  float q0 = bflo(qw.x) * QS, q1 = bfhi(qw.x) * QS;
  float q2 = bflo(qw.y) * QS, q3 = bfhi(qw.y) * QS;

  const int e0 = off[i];
  const int dg = deg[i];

  float denA = 0.f, aA0 = 0.f, aA1 = 0.f, aA2 = 0.f, aA3 = 0.f;
  float denB = 0.f, aB0 = 0.f, aB1 = 0.f, aB2 = 0.f, aB3 = 0.f;

  // one 2-edge step: s0 -> group0 lanes, s1 -> group1 lanes
  auto pair = [&](int s0, int s1, float& den, float& a0, float& a1, float& a2, float& a3) {
    int s = g ? s1 : s0;
    uint2 kv = kvp2[(unsigned)((s << 5) | j)];
    floatx2 k01 = __builtin_amdgcn_cvt_pk_f32_fp8((int)kv.x, false);
    floatx2 v01 = __builtin_amdgcn_cvt_pk_f32_fp8((int)kv.x, true);
    floatx2 k23 = __builtin_amdgcn_cvt_pk_f32_fp8((int)kv.y, false);
    floatx2 v23 = __builtin_amdgcn_cvt_pk_f32_fp8((int)kv.y, true);
    float d = q0 * k01.x + q1 * k01.y + q2 * k23.x + q3 * k23.y;
    d = dpp_add<0xB1>(d);        // quad_perm [1,0,3,2]: xor 1
    d = dpp_add<0x4E>(d);        // quad_perm [2,3,0,1]: xor 2
    d += __shfl_xor(d, 4);       // cross-quad within 8-lane head (LDS pipe)
    float p = exp2f(d);
    den += p;
    a0 += p * v01.x; a1 += p * v01.y; a2 += p * v23.x; a3 += p * v23.y;
  };

  const int nPair = dg >> 1;
  int e = e0;
  int it = 0;
  for (; it + 1 < nPair; it += 2) {
    int s0 = csr[e], s1 = csr[e + 1], s2 = csr[e + 2], s3 = csr[e + 3];
    pair(s0, s1, denA, aA0, aA1, aA2, aA3);
    pair(s2, s3, denB, aB0, aB1, aB2, aB3);
    e += 4;
  }
  if (it < nPair) {
    int s0 = csr[e], s1 = csr[e + 1];
    pair(s0, s1, denA, aA0, aA1, aA2, aA3);
    e += 2;
  }
  if (dg & 1) {
    // single trailing edge: group1 contribution zeroed
    int s0 = csr[e];
    int s = s0;
    uint2 kv = kvp2[(unsigned)((s << 5) | j)];
    floatx2 k01 = __builtin_amdgcn_cvt_pk_f32_fp8((int)kv.x, false);
    floatx2 v01 = __builtin_amdgcn_cvt_pk_f32_fp8((int)kv.x, true);
    floatx2 k23 = __builtin_amdgcn_cvt_pk_f32_fp8((int)kv.y, false);
    floatx2 v23 = __builtin_amdgcn_cvt_pk_f32_fp8((int)kv.y, true);
    float d = q0 * k01.x + q1 * k01.y + q2 * k23.x + q3 * k23.y;
    d = dpp_add<0xB1>(d);
    d = dpp_add<0x4E>(d);
    d += __shfl_xor(d, 4);
    float p = (g == 0) ? exp2f(d) : 0.f;
    denB += p;
    aB0 += p * v01.x; aB1 += p * v01.y; aB2 += p * v23.x; aB3 += p * v23.y;
  }

  // combine chains, then combine the two 32-lane edge groups
  float den = denA + denB;
  float a0 = aA0 + aB0, a1 = aA1 + aB1, a2 = aA2 + aB2, a3 = aA3 + aB3;
  den += __shfl_xor(den, 32);
  a0 += __shfl_xor(a0, 32);
  a1 += __shfl_xor(a1, 32);
  a2 += __shfl_xor(a2, 32);
  a3 += __shfl_xor(a3, 32);
  float inv = 1.f / (den + 1e-16f);
  float o0 = a0 * inv, o1 = a1 * inv, o2 = a2 * inv, o3 = a3 * inv;

  uint2 xw = xr2[(size_t)i * 32 + j];
  float xr0 = bflo(xw.x), xr1 = bfhi(xw.x);
  float xr2v = bflo(xw.y), xr3 = bfhi(xw.y);

  // beta = sigmoid([o | xr | o-xr] . Wb); o identical in both groups -> 32-lane reduce
  float4 wo = *(const float4*)&Wb[4 * j];
  float4 wx = *(const float4*)&Wb[128 + 4 * j];
  float4 wd = *(const float4*)&Wb[256 + 4 * j];
  float c = o0 * wo.x + o1 * wo.y + o2 * wo.z + o3 * wo.w
          + xr0 * wx.x + xr1 * wx.y + xr2v * wx.z + xr3 * wx.w
          + (o0 - xr0) * wd.x + (o1 - xr1) * wd.y + (o2 - xr2v) * wd.z + (o3 - xr3) * wd.w;
  c += __shfl_xor(c, 1);
  c += __shfl_xor(c, 2);
  c += __shfl_xor(c, 4);
  c += __shfl_xor(c, 8);
  c += __shfl_xor(c, 16);
  float beta = 1.f / (1.f + __expf(-c));

  if (g == 0) {
    float h0 = fmaxf(beta * xr0 + (1.f - beta) * o0, 0.f);
    float h1 = fmaxf(beta * xr1 + (1.f - beta) * o1, 0.f);
    float h2 = fmaxf(beta * xr2v + (1.f - beta) * o2, 0.f);
    float h3 = fmaxf(beta * xr3 + (1.f - beta) * o3, 0.f);
    uint2 hw;
    hw.x = pk_bf16(h0, h1);
    hw.y = pk_bf16(h2, h3);
    ((uint2*)q_h)[(size_t)i * 32 + j] = hw;
  }
}

// ---------------- fused mean-pool + MLP ----------------

__global__ __launch_bounds__(128)
void poolmlp_kernel(const unsigned short* __restrict__ h, const int* __restrict__ goff,
                    const float* __restrict__ W1, const float* __restrict__ b1,
                    const float* __restrict__ W2, const float* __restrict__ b2,
                    const float* __restrict__ W3, const float* __restrict__ b3,
                    float* __restrict__ out) {
  int g = blockIdx.x;
  int t = threadIdx.x;
  int n0 = goff[g], cnt = goff[g + 1] - n0;
  float s = 0.f;
  for (int n = n0; n < n0 + cnt; ++n) s += bflo(h[(size_t)n * 128 + t]);
  __shared__ float gv[128];
  __shared__ float t1[64];
  __shared__ float t2[32];
  gv[t] = s / fmaxf((float)cnt, 1.0f);
  __syncthreads();
  if (t < 64) {
    float a = b1[t];
    for (int k = 0; k < 128; ++k) a += gv[k] * W1[k * 64 + t];
    t1[t] = fmaxf(a, 0.f);
  }
  __syncthreads();
  if (t < 32) {
    float a = b2[t];
    for (int k = 0; k < 64; ++k) a += t1[k] * W2[k * 32 + t];
    t2[t] = fmaxf(a, 0.f);
  }
  __syncthreads();
  if (t == 0) {
    float a = b3[0];
    for (int k = 0; k < 32; ++k) a += t2[k] * W3[k];
    out[g] = 1.f / (1.f + __expf(-a));
  }
}

// ---------------- launch ----------------

extern "C" void kernel_launch(void* const* d_in, const int* in_sizes, int n_in,
                              void* d_out, int out_size, void* d_ws, size_t ws_size,
                              hipStream_t stream) {
  const float* x = (const float*)d_in[0];
  const int* edge_index = (const int*)d_in[1];
  const int* batch = (const int*)d_in[2];
  const int N = in_sizes[0] / DH;
  const int E = in_sizes[1] / 2;
  const int G = out_size;
  const int* src = edge_index;
  const int* dst = edge_index + E;

  const float* in_Wq = (const float*)d_in[3];
  const float* in_bq = (const float*)d_in[4];
  const float* in_Wk = (const float*)d_in[5];
  const float* in_bk = (const float*)d_in[6];
  const float* in_Wv = (const float*)d_in[7];
  const float* in_bv = (const float*)d_in[8];
  const float* in_Ws = (const float*)d_in[9];
  const float* in_bs = (const float*)d_in[10];
  const float* in_Wbeta = (const float*)d_in[11];
  const float* blk_Wq = (const float*)d_in[12];
  const float* blk_bq = (const float*)d_in[13];
  const float* blk_Wk = (const float*)d_in[14];
  const float* blk_bk = (const float*)d_in[15];
  const float* blk_Wv = (const float*)d_in[16];
  const float* blk_bv = (const float*)d_in[17];
  const float* blk_Ws = (const float*)d_in[18];
  const float* blk_bs = (const float*)d_in[19];
  const float* blk_Wbeta = (const float*)d_in[20];

  // workspace carve (256B aligned)
  char* p = (char*)d_ws;
  auto take = [&](size_t bytes) { char* r = p; p += (bytes + 255) & ~(size_t)255; return r; };
  __hip_bfloat16* h0 = (__hip_bfloat16*)take((size_t)N * DH * 2);
  __hip_bfloat16* h1 = (__hip_bfloat16*)take((size_t)N * DH * 2);
  unsigned char* kvp = (unsigned char*)take((size_t)N * 256);
  unsigned short* xr = (unsigned short*)take((size_t)N * DH * 2);
  __hip_bfloat16* WT2 = (__hip_bfloat16*)take((size_t)512 * DH * 2);
  float* bcat = (float*)take(512 * 4);
  int* deg    = (int*)take((size_t)N * 4);
  int* off    = (int*)take((size_t)N * 4);
  int* csr    = (int*)take((size_t)E * 4);
  int* part   = (int*)take((size_t)E * 4);
  int* hist   = (int*)take((size_t)NB * NBK * 4);
  int* total  = (int*)take(NBK * 4);
  int* tstart = (int*)take(NBK * 4);
  int* bsumP  = (int*)take(512 * 4);
  int* goff   = (int*)take((size_t)(G + 1) * 4);
  (void)n_in;
  if ((size_t)(p - (char*)d_ws) > ws_size) return;

  const int NBUCK = (N + 127) >> 7;
  const int chunk = (E + NB - 1) / NB;

  // ---- atomic-free CSR build ----
  csr_p1<<<NB, 256, 0, stream>>>(dst, hist, E, chunk);
  csr_p2<<<NBK / 4, 256, 0, stream>>>(hist, total);
  scan1_kernel<<<NBK / 256, 256, 0, stream>>>(total, tstart, bsumP, NBK);
  scan2_kernel<<<1, 512, 0, stream>>>(bsumP, NBK / 256);
  scan3_kernel<<<NBK / 256, 256, 0, stream>>>(tstart, bsumP, NBK);
  csr_p3<<<NB, 256, 0, stream>>>(src, dst, hist, tstart, part, E, chunk);
  csr_p4<<<NBUCK, 256, 0, stream>>>(part, tstart, total, deg, off, csr, N);

  // ---- graph segment offsets (batch sorted) ----
  goff_kernel<<<(G + 256) / 256, 256, 0, stream>>>(batch, goff, N, G);

  cvt_bf16<<<(int)(((size_t)N * DH + 255) / 256), 256, 0, stream>>>(x, h0, N * DH);

  for (int l = 0; l < 4; ++l) {
    const float *Wq, *Wk, *Wv, *Ws, *bq, *bk, *bv, *bs, *Wb;
    if (l == 0) {
      Wq = in_Wq; Wk = in_Wk; Wv = in_Wv; Ws = in_Ws;
      bq = in_bq; bk = in_bk; bv = in_bv; bs = in_bs; Wb = in_Wbeta;
    } else {
      int m = l - 1;
      Wq = blk_Wq + (size_t)m * DH * DH; Wk = blk_Wk + (size_t)m * DH * DH;
      Wv = blk_Wv + (size_t)m * DH * DH; Ws = blk_Ws + (size_t)m * DH * DH;
      bq = blk_bq + (size_t)m * DH; bk = blk_bk + (size_t)m * DH;
      bv = blk_bv + (size_t)m * DH; bs = blk_bs + (size_t)m * DH;
      Wb = blk_Wbeta + (size_t)m * 3 * DH;
    }
    __hip_bfloat16* hin  = (l & 1) ? h1 : h0;
    __hip_bfloat16* qbuf = (l & 1) ? h0 : h1;
    pack_w_kernel<<<65, 256, 0, stream>>>(Wq, Wk, Wv, Ws, bq, bk, bv, bs, WT2, bcat);
    gemm_qkvs<<<(N + 63) / 64, 256, 0, stream>>>((const short*)hin, (const short*)WT2, bcat,
        (unsigned int*)qbuf, (unsigned int*)kvp, (unsigned int*)xr, N);
    attn_kernel<<<(N + 3) / 4, 256, 0, stream>>>((unsigned int*)qbuf, (const uint2*)kvp,
        (const uint2*)xr, off, deg, csr, Wb, N);
  }

  // after 4 layers h lives in h0
  poolmlp_kernel<<<G, 128, 0, stream>>>((const unsigned short*)h0, goff,
      (const float*)d_in[21], (const float*)d_in[22],
      (const float*)d_in[23], (const float*)d_in[24],
      (const float*)d_in[25], (const float*)d_in[26],
      (float*)d_out);
}